// Round 7
// baseline (674.243 us; speedup 1.0000x reference)
//
#include <hip/hip_runtime.h>
#include <hip/hip_bf16.h>

#define NN 10000
#define NE 50000
#define FIN 40
#define FE 10
// L = 64

typedef float f32x4 __attribute__((ext_vector_type(4)));
typedef short s16x8 __attribute__((ext_vector_type(8)));

__device__ __forceinline__ float bcast(float v, int lane) {
    return __uint_as_float(__builtin_amdgcn_readlane(__float_as_uint(v), lane));
}
__device__ __forceinline__ int bcast_i(int v, int lane) {
    return __builtin_amdgcn_readlane(v, lane);
}
__device__ __forceinline__ ushort f2bf(float f) {
    uint u = __float_as_uint(f);
    uint r = (u + 0x7FFFu + ((u >> 16) & 1u)) >> 16;
    return (ushort)r;
}
__device__ __forceinline__ float bf2f(ushort h) {
    return __uint_as_float(((uint)h) << 16);
}

// ---------------- CSR build ----------------
__global__ void k_count(const int* __restrict__ ei, int* __restrict__ deg) {
    int e = blockIdx.x * 256 + threadIdx.x;
    if (e < NE) atomicAdd(&deg[ei[NE + e]], 1);
}

__global__ __launch_bounds__(1024) void k_scan(const int* __restrict__ deg,
                                               int* __restrict__ rowp,
                                               int* __restrict__ fill,
                                               float* __restrict__ invd) {
    __shared__ int wsum[16];
    __shared__ int chunkbase;
    int tid = threadIdx.x, lane = tid & 63, wv = tid >> 6;
    if (tid == 0) chunkbase = 0;
    __syncthreads();
    for (int base = 0; base < NN; base += 1024) {
        int idx = base + tid;
        int v = (idx < NN) ? deg[idx] : 0;
        int s = v;
#pragma unroll
        for (int off = 1; off < 64; off <<= 1) {
            int t = __shfl_up(s, off, 64);
            if (lane >= off) s += t;
        }
        if (lane == 63) wsum[wv] = s;
        __syncthreads();
        int carry = chunkbase;
        if (wv == 0 && lane < 16) {
            int x = wsum[lane];
#pragma unroll
            for (int off = 1; off < 16; off <<= 1) {
                int t = __shfl_up(x, off, 64);
                if (lane >= off) x += t;
            }
            wsum[lane] = x;  // inclusive over waves
        }
        __syncthreads();
        int wpre = (wv == 0) ? 0 : wsum[wv - 1];
        int incl = carry + wpre + s;
        if (idx < NN) {
            rowp[idx] = incl - v;
            fill[idx] = incl - v;
            invd[idx] = 1.0f / (float)(v > 0 ? v : 1);
        }
        __syncthreads();
        if (tid == 0) chunkbase = carry + wsum[15];
        __syncthreads();
    }
    if (tid == 0) rowp[NN] = NE;
}

__global__ void k_fill(const int* __restrict__ ei, int* __restrict__ fill,
                       int* __restrict__ csrs, int* __restrict__ csre) {
    int e = blockIdx.x * 256 + threadIdx.x;
    if (e < NE) {
        int d = ei[NE + e];
        int p = atomicAdd(&fill[d], 1);
        csrs[p] = ei[e];
        csre[p] = e;
    }
}

// ---------------- W2 split-bf16, transposed to [o][ki] (ki = k*64+i) ----------------
__global__ __launch_bounds__(256) void k_w2f(const float* __restrict__ n2w,
                                             ushort* __restrict__ W2FH,
                                             ushort* __restrict__ W2FL) {
    int lane = threadIdx.x & 63, wvl = threadIdx.x >> 6;
    int ki = blockIdx.x * 4 + wvl;
    float v = n2w[(size_t)ki * 64 + lane];
    ushort hi = f2bf(v);
    ushort lo = f2bf(v - bf2f(hi));
    W2FH[(size_t)lane * 4096 + ki] = hi;
    W2FL[(size_t)lane * 4096 + ki] = lo;
}

// ---------------- edge MLP: hE = relu(edge_attr @ nn1_w + nn1_b) ----------------
__global__ __launch_bounds__(256) void k_edge_h(const float* __restrict__ ea,
                                                const float* __restrict__ w1,
                                                const float* __restrict__ b1,
                                                float* __restrict__ hE) {
    int lane = threadIdx.x & 63, wv = threadIdx.x >> 6;
    int e = blockIdx.x * 4 + wv;
    float av = (lane < FE) ? ea[e * FE + lane] : 0.f;
    float acc = b1[lane];
#pragma unroll
    for (int j = 0; j < FE; ++j) acc += bcast(av, j) * w1[j * 64 + lane];
    hE[e * 64 + lane] = fmaxf(acc, 0.f);
}

// ---------------- lin0 ----------------
__global__ __launch_bounds__(256) void k_lin0(const float* __restrict__ x,
                                              const float* __restrict__ w0,
                                              const float* __restrict__ b0,
                                              float* __restrict__ F) {
    int lane = threadIdx.x & 63, wv = threadIdx.x >> 6;
    int n = blockIdx.x * 4 + wv;
    float xv = (lane < FIN) ? x[n * FIN + lane] : 0.f;
    float acc = b0[lane];
#pragma unroll
    for (int k = 0; k < FIN; ++k) acc += bcast(xv, k) * w0[k * 64 + lane];
    F[n * 64 + lane] = fmaxf(acc, 0.f);
}

// ---------------- fused NNConv + GRU via MFMA ----------------
// 16 waves = 16 nodes/block, 625 blocks. amdgpu_waves_per_eu(4,4) -> one
// block/CU, 128-VGPR budget (R2-R5 were pinned at 64 and spilled hoisted
// MFMA operands: 35 MB WRITE_SIZE signature).
// Phase A: coalesced per-lane loads of csr indices (64 at once, readlane'd),
// hE rows and F rows; G[64] in VGPR (lane=i), k-loop fully unrolled.
// MFMA: 4 statically-unrolled chunks (static G indexing), s8 unroll 2 to cap
// operand hoisting. Epilogue: mean+nn2_b+root+relu -> GRU -> Fout ping-pong.
__global__ __launch_bounds__(1024)
__attribute__((amdgpu_waves_per_eu(4, 4))) void k_mp(
    const float* __restrict__ F, const float* __restrict__ hE,
    const int* __restrict__ rowp, const int* __restrict__ csrs,
    const int* __restrict__ csre,
    const ushort* __restrict__ W2FH, const ushort* __restrict__ W2FL,
    const float* __restrict__ B2, const float* __restrict__ invd,
    const float* __restrict__ Wroot, const float* __restrict__ broot,
    const float* __restrict__ Wih, const float* __restrict__ Whh,
    const float* __restrict__ bih, const float* __restrict__ bhh,
    float* __restrict__ Fout) {
    __shared__ __align__(16) char smem[37120];
    ushort(*GH)[1032] = (ushort(*)[1032])smem;            // [16][1032] 33024 B
    float(*Us)[64] = (float(*)[64])(smem + 33024);        // [16][64] 4096 B
    float(*Red)[256] = (float(*)[256])smem;               // union over GH 16KB
    float(*Agg)[64] = (float(*)[64])(smem + 16384);       // union over GH 4KB

    int tid = threadIdx.x, lane = tid & 63, wv = tid >> 6;
    int n = __builtin_amdgcn_readfirstlane(blockIdx.x * 16 + wv);
    int beg = __builtin_amdgcn_readfirstlane(rowp[n]);
    int end = __builtin_amdgcn_readfirstlane(rowp[n + 1]);

    // ---- phase A: G[k] (lane=i) = sum_e hE[e][k] * F[src][i] ----
    float G[64];
#pragma unroll
    for (int k = 0; k < 64; ++k) G[k] = 0.f;
    float usum = 0.f;
    {
        int p0 = beg + lane;
        int sl = (p0 < end) ? csrs[p0] : 0;
        int el = (p0 < end) ? csre[p0] : 0;
        int nb = min(end - beg, 64);
        for (int j = 0; j < nb; ++j) {
            int s = bcast_i(sl, j);
            int e = bcast_i(el, j);
            float u = F[(size_t)s * 64 + lane];
            float hv = hE[(size_t)e * 64 + lane];
            usum += u;
#pragma unroll
            for (int k = 0; k < 64; ++k) G[k] = fmaf(bcast(hv, k), u, G[k]);
        }
        for (int p = beg + 64; p < end; ++p) {  // deg>64: astronomically rare
            int s = __builtin_amdgcn_readfirstlane(csrs[p]);
            int e = __builtin_amdgcn_readfirstlane(csre[p]);
            float u = F[(size_t)s * 64 + lane];
            float hv = hE[(size_t)e * 64 + lane];
            usum += u;
#pragma unroll
            for (int k = 0; k < 64; ++k) G[k] = fmaf(bcast(hv, k), u, G[k]);
        }
    }
    Us[wv][lane] = usum;

    // ---- MFMA phase: 4 static chunks ----
    f32x4 acc = {0.f, 0.f, 0.f, 0.f};
    int otile = wv & 3, kq = wv >> 2;
    int arow = lane & 15, agrp = lane >> 4;
    int o = otile * 16 + arow;
    const ushort* bhbase = W2FH + (size_t)o * 4096;
    const ushort* blbase = W2FL + (size_t)o * 4096;
#pragma unroll
    for (int c = 0; c < 4; ++c) {
#pragma unroll
        for (int kk = 0; kk < 16; ++kk)
            GH[wv][kk * 64 + lane] = f2bf(G[c * 16 + kk]);
        __syncthreads();
#pragma unroll 2
        for (int s8 = 0; s8 < 8; ++s8) {
            int ki = (kq * 8 + s8) * 32 + agrp * 8;
            s16x8 ah = *(const s16x8*)&GH[arow][ki];
            s16x8 bh = *(const s16x8*)&bhbase[c * 1024 + ki];
            s16x8 bl = *(const s16x8*)&blbase[c * 1024 + ki];
            acc = __builtin_amdgcn_mfma_f32_16x16x32_bf16(ah, bh, acc, 0, 0, 0);
            acc = __builtin_amdgcn_mfma_f32_16x16x32_bf16(ah, bl, acc, 0, 0, 0);
        }
        __syncthreads();
    }

    // ---- reduce partial D over the 4 kq groups ----
    *(f32x4*)&Red[wv][lane * 4] = acc;
    __syncthreads();
    if (wv < 4) {
        int t = wv;
        f32x4 s0 = *(f32x4*)&Red[t][lane * 4];
        f32x4 s1 = *(f32x4*)&Red[t + 4][lane * 4];
        f32x4 s2 = *(f32x4*)&Red[t + 8][lane * 4];
        f32x4 s3 = *(f32x4*)&Red[t + 12][lane * 4];
        f32x4 ss = s0 + s1 + s2 + s3;
        // D[row=node=(lane>>4)*4+r][col=o=t*16+(lane&15)]
#pragma unroll
        for (int r = 0; r < 4; ++r)
            Agg[(lane >> 4) * 4 + r][t * 16 + (lane & 15)] = ss[r];
    }
    __syncthreads();

    // ---- epilogue per node-wave: mean + nn2_b + root -> relu -> m ----
    float b2t = 0.f;
#pragma unroll 8
    for (int i = 0; i < 64; ++i) b2t = fmaf(Us[wv][i], B2[i * 64 + lane], b2t);
    float a = (Agg[wv][lane] + b2t) * invd[n];
    float fv = F[(size_t)n * 64 + lane];
    float r = broot[lane];
#pragma unroll
    for (int k = 0; k < 64; ++k) r = fmaf(bcast(fv, k), Wroot[k * 64 + lane], r);
    float m = fmaxf(a + r, 0.f);

    // ---- fused single-step GRU: h' = (1-z)*ng + z*h ----
    float sr = bih[lane] + bhh[lane];
    float sz = bih[64 + lane] + bhh[64 + lane];
    float gin = bih[128 + lane];
    float ghn = bhh[128 + lane];
#pragma unroll
    for (int k = 0; k < 64; ++k) {
        float mk = bcast(m, k), hk = bcast(fv, k);
        const float* wi = &Wih[k * 192];
        const float* wh = &Whh[k * 192];
        sr = fmaf(mk, wi[lane], fmaf(hk, wh[lane], sr));
        sz = fmaf(mk, wi[64 + lane], fmaf(hk, wh[64 + lane], sz));
        gin = fmaf(mk, wi[128 + lane], gin);
        ghn = fmaf(hk, wh[128 + lane], ghn);
    }
    float rr = 1.f / (1.f + __expf(-sr));
    float zz = 1.f / (1.f + __expf(-sz));
    float ng = tanhf(gin + rr * ghn);
    Fout[(size_t)n * 64 + lane] = (1.f - zz) * ng + zz * fv;
}

// ---------------- final ----------------
__global__ __launch_bounds__(256) void k_final(const float* __restrict__ F,
                                               const float* __restrict__ W1,
                                               const float* __restrict__ b1f,
                                               const float* __restrict__ W2l,
                                               const float* __restrict__ b2f,
                                               float* __restrict__ out) {
    int lane = threadIdx.x & 63, wv = threadIdx.x >> 6;
    int n = blockIdx.x * 4 + wv;
    float fv = F[n * 64 + lane];
    float acc = b1f[lane];
#pragma unroll
    for (int k = 0; k < 64; ++k) acc += bcast(fv, k) * W1[k * 64 + lane];
    acc = fmaxf(acc, 0.f);
    float p = acc * W2l[lane];
#pragma unroll
    for (int off = 32; off; off >>= 1) p += __shfl_xor(p, off, 64);
    if (lane == 0) out[n] = p + b2f[0];
}

extern "C" void kernel_launch(void* const* d_in, const int* in_sizes, int n_in,
                              void* d_out, int out_size, void* d_ws, size_t ws_size,
                              hipStream_t stream) {
    const float* x = (const float*)d_in[0];
    const int* ei = (const int*)d_in[1];
    const float* ea = (const float*)d_in[2];
    const float* l0w = (const float*)d_in[3];
    const float* l0b = (const float*)d_in[4];
    const float* n1w = (const float*)d_in[5];
    const float* n1b = (const float*)d_in[6];
    const float* n2w = (const float*)d_in[7];
    const float* n2b = (const float*)d_in[8];
    const float* cr = (const float*)d_in[9];
    const float* cb = (const float*)d_in[10];
    const float* wih = (const float*)d_in[11];
    const float* whh = (const float*)d_in[12];
    const float* bih = (const float*)d_in[13];
    const float* bhh = (const float*)d_in[14];
    const float* l1w = (const float*)d_in[15];
    const float* l1b = (const float*)d_in[16];
    const float* l2w = (const float*)d_in[17];
    const float* l2b = (const float*)d_in[18];

    char* w = (char*)d_ws;
    size_t off = 0;
    float* F0 = (float*)(w + off); off += (size_t)NN * 64 * 4;
    float* F1 = (float*)(w + off); off += (size_t)NN * 64 * 4;
    float* hE = (float*)(w + off); off += (size_t)NE * 64 * 4;
    ushort* W2FH = (ushort*)(w + off); off += (size_t)64 * 4096 * 2;
    ushort* W2FL = (ushort*)(w + off); off += (size_t)64 * 4096 * 2;
    float* invd = (float*)(w + off); off += (size_t)NN * 4;
    int* deg = (int*)(w + off); off += (size_t)NN * 4;
    int* rowp = (int*)(w + off); off += (size_t)(NN + 1) * 4 + 252; off &= ~(size_t)255;
    int* fill = (int*)(w + off); off += (size_t)NN * 4;
    int* csrs = (int*)(w + off); off += (size_t)NE * 4;
    int* csre = (int*)(w + off); off += (size_t)NE * 4;

    hipMemsetAsync(deg, 0, NN * 4, stream);
    k_count<<<(NE + 255) / 256, 256, 0, stream>>>(ei, deg);
    k_scan<<<1, 1024, 0, stream>>>(deg, rowp, fill, invd);
    k_fill<<<(NE + 255) / 256, 256, 0, stream>>>(ei, fill, csrs, csre);
    k_w2f<<<1024, 256, 0, stream>>>(n2w, W2FH, W2FL);
    k_edge_h<<<NE / 4, 256, 0, stream>>>(ea, n1w, n1b, hE);
    k_lin0<<<NN / 4, 256, 0, stream>>>(x, l0w, l0b, F0);
    float* Fcur = F0;
    float* Fnxt = F1;
    for (int it = 0; it < 3; ++it) {
        k_mp<<<NN / 16, 1024, 0, stream>>>(Fcur, hE, rowp, csrs, csre, W2FH,
                                           W2FL, n2b, invd, cr, cb, wih, whh,
                                           bih, bhh, Fnxt);
        float* t = Fcur; Fcur = Fnxt; Fnxt = t;
    }
    k_final<<<NN / 4, 256, 0, stream>>>(Fcur, l1w, l1b, l2w, l2b, (float*)d_out);
}

// Round 8
// 462.768 us; speedup vs baseline: 1.4570x; 1.4570x over previous
//
#include <hip/hip_runtime.h>
#include <hip/hip_bf16.h>

#define NN 10000
#define NE 50000
#define FIN 40
#define FE 10
// L = 64

typedef float f32x4 __attribute__((ext_vector_type(4)));
typedef short s16x8 __attribute__((ext_vector_type(8)));

__device__ __forceinline__ float bcast(float v, int lane) {
    return __uint_as_float(__builtin_amdgcn_readlane(__float_as_uint(v), lane));
}
__device__ __forceinline__ int bcast_i(int v, int lane) {
    return __builtin_amdgcn_readlane(v, lane);
}
__device__ __forceinline__ ushort f2bf(float f) {
    uint u = __float_as_uint(f);
    uint r = (u + 0x7FFFu + ((u >> 16) & 1u)) >> 16;
    return (ushort)r;
}
__device__ __forceinline__ float bf2f(ushort h) {
    return __uint_as_float(((uint)h) << 16);
}

// ---------------- CSR build ----------------
__global__ void k_count(const int* __restrict__ ei, int* __restrict__ deg) {
    int e = blockIdx.x * 256 + threadIdx.x;
    if (e < NE) atomicAdd(&deg[ei[NE + e]], 1);
}

__global__ __launch_bounds__(1024) void k_scan(const int* __restrict__ deg,
                                               int* __restrict__ rowp,
                                               int* __restrict__ fill,
                                               float* __restrict__ invd) {
    __shared__ int wsum[16];
    __shared__ int chunkbase;
    int tid = threadIdx.x, lane = tid & 63, wv = tid >> 6;
    if (tid == 0) chunkbase = 0;
    __syncthreads();
    for (int base = 0; base < NN; base += 1024) {
        int idx = base + tid;
        int v = (idx < NN) ? deg[idx] : 0;
        int s = v;
#pragma unroll
        for (int off = 1; off < 64; off <<= 1) {
            int t = __shfl_up(s, off, 64);
            if (lane >= off) s += t;
        }
        if (lane == 63) wsum[wv] = s;
        __syncthreads();
        int carry = chunkbase;
        if (wv == 0 && lane < 16) {
            int x = wsum[lane];
#pragma unroll
            for (int off = 1; off < 16; off <<= 1) {
                int t = __shfl_up(x, off, 64);
                if (lane >= off) x += t;
            }
            wsum[lane] = x;  // inclusive over waves
        }
        __syncthreads();
        int wpre = (wv == 0) ? 0 : wsum[wv - 1];
        int incl = carry + wpre + s;
        if (idx < NN) {
            rowp[idx] = incl - v;
            fill[idx] = incl - v;
            invd[idx] = 1.0f / (float)(v > 0 ? v : 1);
        }
        __syncthreads();
        if (tid == 0) chunkbase = carry + wsum[15];
        __syncthreads();
    }
    if (tid == 0) rowp[NN] = NE;
}

__global__ void k_fill(const int* __restrict__ ei, int* __restrict__ fill,
                       int* __restrict__ csrs, int* __restrict__ csre) {
    int e = blockIdx.x * 256 + threadIdx.x;
    if (e < NE) {
        int d = ei[NE + e];
        int p = atomicAdd(&fill[d], 1);
        csrs[p] = ei[e];
        csre[p] = e;
    }
}

// ---------------- W2 split-bf16, transposed to [o][ki] (ki = k*64+i) ----------------
__global__ __launch_bounds__(256) void k_w2f(const float* __restrict__ n2w,
                                             ushort* __restrict__ W2FH,
                                             ushort* __restrict__ W2FL) {
    int lane = threadIdx.x & 63, wvl = threadIdx.x >> 6;
    int ki = blockIdx.x * 4 + wvl;
    float v = n2w[(size_t)ki * 64 + lane];
    ushort hi = f2bf(v);
    ushort lo = f2bf(v - bf2f(hi));
    W2FH[(size_t)lane * 4096 + ki] = hi;
    W2FL[(size_t)lane * 4096 + ki] = lo;
}

// ---------------- edge MLP: hE = relu(edge_attr @ nn1_w + nn1_b) ----------------
__global__ __launch_bounds__(256) void k_edge_h(const float* __restrict__ ea,
                                                const float* __restrict__ w1,
                                                const float* __restrict__ b1,
                                                float* __restrict__ hE) {
    int lane = threadIdx.x & 63, wv = threadIdx.x >> 6;
    int e = blockIdx.x * 4 + wv;
    float av = (lane < FE) ? ea[e * FE + lane] : 0.f;
    float acc = b1[lane];
#pragma unroll
    for (int j = 0; j < FE; ++j) acc += bcast(av, j) * w1[j * 64 + lane];
    hE[e * 64 + lane] = fmaxf(acc, 0.f);
}

// ---------------- lin0 ----------------
__global__ __launch_bounds__(256) void k_lin0(const float* __restrict__ x,
                                              const float* __restrict__ w0,
                                              const float* __restrict__ b0,
                                              float* __restrict__ F) {
    int lane = threadIdx.x & 63, wv = threadIdx.x >> 6;
    int n = blockIdx.x * 4 + wv;
    float xv = (lane < FIN) ? x[n * FIN + lane] : 0.f;
    float acc = b0[lane];
#pragma unroll
    for (int k = 0; k < FIN; ++k) acc += bcast(xv, k) * w0[k * 64 + lane];
    F[n * 64 + lane] = fmaxf(acc, 0.f);
}

// ---------------- gather: G[n][k*64+i] = sum_e hE[e][k]*F[src][i] (bf16 out) ----
// 256 thr = 4 waves = 4 nodes/block (the R0-proven clean-regalloc shape).
__global__ __launch_bounds__(256) void k_gather(
    const float* __restrict__ F, const float* __restrict__ hE,
    const int* __restrict__ rowp, const int* __restrict__ csrs,
    const int* __restrict__ csre,
    ushort* __restrict__ GH, float* __restrict__ Usb) {
    int tid = threadIdx.x, lane = tid & 63, wv = tid >> 6;
    int n = __builtin_amdgcn_readfirstlane(blockIdx.x * 4 + wv);
    int beg = __builtin_amdgcn_readfirstlane(rowp[n]);
    int end = __builtin_amdgcn_readfirstlane(rowp[n + 1]);

    float G[64];
#pragma unroll
    for (int k = 0; k < 64; ++k) G[k] = 0.f;
    float usum = 0.f;
    {
        int p0 = beg + lane;
        int sl = (p0 < end) ? csrs[p0] : 0;
        int el = (p0 < end) ? csre[p0] : 0;
        int nb = min(end - beg, 64);
        for (int j = 0; j < nb; ++j) {
            int s = bcast_i(sl, j);
            int e = bcast_i(el, j);
            float u = F[(size_t)s * 64 + lane];
            float hv = hE[(size_t)e * 64 + lane];
            usum += u;
#pragma unroll
            for (int k = 0; k < 64; ++k) G[k] = fmaf(bcast(hv, k), u, G[k]);
        }
        for (int p = beg + 64; p < end; ++p) {  // deg>64: rare
            int s = __builtin_amdgcn_readfirstlane(csrs[p]);
            int e = __builtin_amdgcn_readfirstlane(csre[p]);
            float u = F[(size_t)s * 64 + lane];
            float hv = hE[(size_t)e * 64 + lane];
            usum += u;
#pragma unroll
            for (int k = 0; k < 64; ++k) G[k] = fmaf(bcast(hv, k), u, G[k]);
        }
    }
    Usb[(size_t)n * 64 + lane] = usum;
    ushort* gout = GH + (size_t)n * 4096 + lane;
#pragma unroll
    for (int k = 0; k < 64; ++k) gout[k * 64] = f2bf(G[k]);
}

// ---------------- contract: Agg = GH @ W2F^T via MFMA + fused epilogue/GRU ----
// 625 blocks x 256 thr; block = 16 nodes, wave wv = o-tile wv. A staged in
// LDS (8 chunks of 512 ki). Epilogue: 4 nodes/wave, weight rows loaded once
// per 4 nodes (4x less L2 traffic on Wroot/B2/Wih/Whh).
__global__ __launch_bounds__(256) void k_contract(
    const ushort* __restrict__ GH, const ushort* __restrict__ W2FH,
    const ushort* __restrict__ W2FL, const float* __restrict__ Usb,
    const float* __restrict__ B2, const float* __restrict__ invd,
    const float* __restrict__ F, const float* __restrict__ Wroot,
    const float* __restrict__ broot, const float* __restrict__ Wih,
    const float* __restrict__ Whh, const float* __restrict__ bih,
    const float* __restrict__ bhh, float* __restrict__ Fout) {
    __shared__ __align__(16) ushort As[16 * 520];  // 16640 B (row pad 520)
    __shared__ float Agg[16][64];                  // 4096 B
    int tid = threadIdx.x, lane = tid & 63, wv = tid >> 6;
    int n0 = __builtin_amdgcn_readfirstlane(blockIdx.x * 16);
    int arow = lane & 15, agrp = lane >> 4;
    int o = wv * 16 + arow;
    const ushort* bh0 = W2FH + (size_t)o * 4096;
    const ushort* bl0 = W2FL + (size_t)o * 4096;

    f32x4 acc = {0.f, 0.f, 0.f, 0.f};
#pragma unroll 1
    for (int ch = 0; ch < 8; ++ch) {
        int c0 = ch * 512;
#pragma unroll
        for (int rep = 0; rep < 4; ++rep) {
            int off = rep * 2048 + tid * 8;
            int row = off >> 9, col = off & 511;
            *(s16x8*)&As[row * 520 + col] =
                *(const s16x8*)&GH[(size_t)(n0 + row) * 4096 + c0 + col];
        }
        __syncthreads();
#pragma unroll 4
        for (int s = 0; s < 16; ++s) {
            int kil = s * 32 + agrp * 8;
            s16x8 ah = *(const s16x8*)&As[arow * 520 + kil];
            s16x8 bh = *(const s16x8*)&bh0[c0 + kil];
            s16x8 bl = *(const s16x8*)&bl0[c0 + kil];
            acc = __builtin_amdgcn_mfma_f32_16x16x32_bf16(ah, bh, acc, 0, 0, 0);
            acc = __builtin_amdgcn_mfma_f32_16x16x32_bf16(ah, bl, acc, 0, 0, 0);
        }
        __syncthreads();
    }
    // D[row=node=agrp*4+r][col=o]
#pragma unroll
    for (int r = 0; r < 4; ++r) Agg[agrp * 4 + r][wv * 16 + arow] = acc[r];
    __syncthreads();

    // ---- epilogue: nodes nq..nq+3 for this wave ----
    int nq = n0 + wv * 4;
    float fv[4], uv[4], aa[4], rt[4], bt[4];
#pragma unroll
    for (int q = 0; q < 4; ++q) {
        fv[q] = F[(size_t)(nq + q) * 64 + lane];
        uv[q] = Usb[(size_t)(nq + q) * 64 + lane];
        aa[q] = Agg[wv * 4 + q][lane];
        rt[q] = broot[lane];
        bt[q] = 0.f;
    }
#pragma unroll 8
    for (int k = 0; k < 64; ++k) {
        float wr = Wroot[k * 64 + lane];
        float b2 = B2[k * 64 + lane];
#pragma unroll
        for (int q = 0; q < 4; ++q) {
            rt[q] = fmaf(bcast(fv[q], k), wr, rt[q]);
            bt[q] = fmaf(bcast(uv[q], k), b2, bt[q]);
        }
    }
    float m[4];
#pragma unroll
    for (int q = 0; q < 4; ++q)
        m[q] = fmaxf((aa[q] + bt[q]) * invd[nq + q] + rt[q], 0.f);

    float sr[4], sz[4], gn[4], gh[4];
#pragma unroll
    for (int q = 0; q < 4; ++q) {
        sr[q] = bih[lane] + bhh[lane];
        sz[q] = bih[64 + lane] + bhh[64 + lane];
        gn[q] = bih[128 + lane];
        gh[q] = bhh[128 + lane];
    }
#pragma unroll 8
    for (int k = 0; k < 64; ++k) {
        float wi0 = Wih[k * 192 + lane];
        float wi1 = Wih[k * 192 + 64 + lane];
        float wi2 = Wih[k * 192 + 128 + lane];
        float wh0 = Whh[k * 192 + lane];
        float wh1 = Whh[k * 192 + 64 + lane];
        float wh2 = Whh[k * 192 + 128 + lane];
#pragma unroll
        for (int q = 0; q < 4; ++q) {
            float mk = bcast(m[q], k), hk = bcast(fv[q], k);
            sr[q] = fmaf(mk, wi0, fmaf(hk, wh0, sr[q]));
            sz[q] = fmaf(mk, wi1, fmaf(hk, wh1, sz[q]));
            gn[q] = fmaf(mk, wi2, gn[q]);
            gh[q] = fmaf(hk, wh2, gh[q]);
        }
    }
#pragma unroll
    for (int q = 0; q < 4; ++q) {
        float rr = 1.f / (1.f + __expf(-sr[q]));
        float zz = 1.f / (1.f + __expf(-sz[q]));
        float ng = tanhf(gn[q] + rr * gh[q]);
        Fout[(size_t)(nq + q) * 64 + lane] = (1.f - zz) * ng + zz * fv[q];
    }
}

// ---------------- final ----------------
__global__ __launch_bounds__(256) void k_final(const float* __restrict__ F,
                                               const float* __restrict__ W1,
                                               const float* __restrict__ b1f,
                                               const float* __restrict__ W2l,
                                               const float* __restrict__ b2f,
                                               float* __restrict__ out) {
    int lane = threadIdx.x & 63, wv = threadIdx.x >> 6;
    int n = blockIdx.x * 4 + wv;
    float fv = F[n * 64 + lane];
    float acc = b1f[lane];
#pragma unroll
    for (int k = 0; k < 64; ++k) acc += bcast(fv, k) * W1[k * 64 + lane];
    acc = fmaxf(acc, 0.f);
    float p = acc * W2l[lane];
#pragma unroll
    for (int off = 32; off; off >>= 1) p += __shfl_xor(p, off, 64);
    if (lane == 0) out[n] = p + b2f[0];
}

extern "C" void kernel_launch(void* const* d_in, const int* in_sizes, int n_in,
                              void* d_out, int out_size, void* d_ws, size_t ws_size,
                              hipStream_t stream) {
    const float* x = (const float*)d_in[0];
    const int* ei = (const int*)d_in[1];
    const float* ea = (const float*)d_in[2];
    const float* l0w = (const float*)d_in[3];
    const float* l0b = (const float*)d_in[4];
    const float* n1w = (const float*)d_in[5];
    const float* n1b = (const float*)d_in[6];
    const float* n2w = (const float*)d_in[7];
    const float* n2b = (const float*)d_in[8];
    const float* cr = (const float*)d_in[9];
    const float* cb = (const float*)d_in[10];
    const float* wih = (const float*)d_in[11];
    const float* whh = (const float*)d_in[12];
    const float* bih = (const float*)d_in[13];
    const float* bhh = (const float*)d_in[14];
    const float* l1w = (const float*)d_in[15];
    const float* l1b = (const float*)d_in[16];
    const float* l2w = (const float*)d_in[17];
    const float* l2b = (const float*)d_in[18];

    char* w = (char*)d_ws;
    size_t off = 0;
    float* F0 = (float*)(w + off); off += (size_t)NN * 64 * 4;
    float* F1 = (float*)(w + off); off += (size_t)NN * 64 * 4;
    float* hE = (float*)(w + off); off += (size_t)NE * 64 * 4;
    ushort* W2FH = (ushort*)(w + off); off += (size_t)64 * 4096 * 2;
    ushort* W2FL = (ushort*)(w + off); off += (size_t)64 * 4096 * 2;
    ushort* GH = (ushort*)(w + off); off += (size_t)NN * 4096 * 2;   // 80 MB
    float* Usb = (float*)(w + off); off += (size_t)NN * 64 * 4;      // 2.5 MB
    float* invd = (float*)(w + off); off += (size_t)NN * 4;
    int* deg = (int*)(w + off); off += (size_t)NN * 4;
    int* rowp = (int*)(w + off); off += (size_t)(NN + 1) * 4 + 252; off &= ~(size_t)255;
    int* fill = (int*)(w + off); off += (size_t)NN * 4;
    int* csrs = (int*)(w + off); off += (size_t)NE * 4;
    int* csre = (int*)(w + off); off += (size_t)NE * 4;

    hipMemsetAsync(deg, 0, NN * 4, stream);
    k_count<<<(NE + 255) / 256, 256, 0, stream>>>(ei, deg);
    k_scan<<<1, 1024, 0, stream>>>(deg, rowp, fill, invd);
    k_fill<<<(NE + 255) / 256, 256, 0, stream>>>(ei, fill, csrs, csre);
    k_w2f<<<1024, 256, 0, stream>>>(n2w, W2FH, W2FL);
    k_edge_h<<<NE / 4, 256, 0, stream>>>(ea, n1w, n1b, hE);
    k_lin0<<<NN / 4, 256, 0, stream>>>(x, l0w, l0b, F0);
    float* Fcur = F0;
    float* Fnxt = F1;
    for (int it = 0; it < 3; ++it) {
        k_gather<<<NN / 4, 256, 0, stream>>>(Fcur, hE, rowp, csrs, csre, GH, Usb);
        k_contract<<<NN / 16, 256, 0, stream>>>(GH, W2FH, W2FL, Usb, n2b, invd,
                                                Fcur, cr, cb, wih, whh, bih,
                                                bhh, Fnxt);
        float* t = Fcur; Fcur = Fnxt; Fnxt = t;
    }
    k_final<<<NN / 4, 256, 0, stream>>>(Fcur, l1w, l1b, l2w, l2b, (float*)d_out);
}

// Round 9
// 451.368 us; speedup vs baseline: 1.4938x; 1.0253x over previous
//
#include <hip/hip_runtime.h>
#include <hip/hip_bf16.h>

#define NN 10000
#define NE 50000
#define FIN 40
#define FE 10
// L = 64

typedef float f32x4 __attribute__((ext_vector_type(4)));
typedef short s16x8 __attribute__((ext_vector_type(8)));

__device__ __forceinline__ float bcast(float v, int lane) {
    return __uint_as_float(__builtin_amdgcn_readlane(__float_as_uint(v), lane));
}
__device__ __forceinline__ int bcast_i(int v, int lane) {
    return __builtin_amdgcn_readlane(v, lane);
}
__device__ __forceinline__ ushort f2bf(float f) {
    uint u = __float_as_uint(f);
    uint r = (u + 0x7FFFu + ((u >> 16) & 1u)) >> 16;
    return (ushort)r;
}
__device__ __forceinline__ float bf2f(ushort h) {
    return __uint_as_float(((uint)h) << 16);
}

// ---------------- CSR build ----------------
__global__ void k_count(const int* __restrict__ ei, int* __restrict__ deg) {
    int e = blockIdx.x * 256 + threadIdx.x;
    if (e < NE) atomicAdd(&deg[ei[NE + e]], 1);
}

__global__ __launch_bounds__(1024) void k_scan(const int* __restrict__ deg,
                                               int* __restrict__ rowp,
                                               int* __restrict__ fill,
                                               float* __restrict__ invd) {
    __shared__ int wsum[16];
    __shared__ int chunkbase;
    int tid = threadIdx.x, lane = tid & 63, wv = tid >> 6;
    if (tid == 0) chunkbase = 0;
    __syncthreads();
    for (int base = 0; base < NN; base += 1024) {
        int idx = base + tid;
        int v = (idx < NN) ? deg[idx] : 0;
        int s = v;
#pragma unroll
        for (int off = 1; off < 64; off <<= 1) {
            int t = __shfl_up(s, off, 64);
            if (lane >= off) s += t;
        }
        if (lane == 63) wsum[wv] = s;
        __syncthreads();
        int carry = chunkbase;
        if (wv == 0 && lane < 16) {
            int x = wsum[lane];
#pragma unroll
            for (int off = 1; off < 16; off <<= 1) {
                int t = __shfl_up(x, off, 64);
                if (lane >= off) x += t;
            }
            wsum[lane] = x;  // inclusive over waves
        }
        __syncthreads();
        int wpre = (wv == 0) ? 0 : wsum[wv - 1];
        int incl = carry + wpre + s;
        if (idx < NN) {
            rowp[idx] = incl - v;
            fill[idx] = incl - v;
            invd[idx] = 1.0f / (float)(v > 0 ? v : 1);
        }
        __syncthreads();
        if (tid == 0) chunkbase = carry + wsum[15];
        __syncthreads();
    }
    if (tid == 0) rowp[NN] = NE;
}

__global__ void k_fill(const int* __restrict__ ei, int* __restrict__ fill,
                       int* __restrict__ csrs, int* __restrict__ csre) {
    int e = blockIdx.x * 256 + threadIdx.x;
    if (e < NE) {
        int d = ei[NE + e];
        int p = atomicAdd(&fill[d], 1);
        csrs[p] = ei[e];
        csre[p] = e;
    }
}

// ---------------- W2 split-bf16, transposed to [o][ki] (ki = k*64+i) ----------------
__global__ __launch_bounds__(256) void k_w2f(const float* __restrict__ n2w,
                                             ushort* __restrict__ W2FH,
                                             ushort* __restrict__ W2FL) {
    int lane = threadIdx.x & 63, wvl = threadIdx.x >> 6;
    int ki = blockIdx.x * 4 + wvl;
    float v = n2w[(size_t)ki * 64 + lane];
    ushort hi = f2bf(v);
    ushort lo = f2bf(v - bf2f(hi));
    W2FH[(size_t)lane * 4096 + ki] = hi;
    W2FL[(size_t)lane * 4096 + ki] = lo;
}

// ---------------- edge MLP: hE = relu(edge_attr @ nn1_w + nn1_b) ----------------
__global__ __launch_bounds__(256) void k_edge_h(const float* __restrict__ ea,
                                                const float* __restrict__ w1,
                                                const float* __restrict__ b1,
                                                float* __restrict__ hE) {
    int lane = threadIdx.x & 63, wv = threadIdx.x >> 6;
    int e = blockIdx.x * 4 + wv;
    float av = (lane < FE) ? ea[e * FE + lane] : 0.f;
    float acc = b1[lane];
#pragma unroll
    for (int j = 0; j < FE; ++j) acc += bcast(av, j) * w1[j * 64 + lane];
    hE[e * 64 + lane] = fmaxf(acc, 0.f);
}

// ---------------- lin0 ----------------
__global__ __launch_bounds__(256) void k_lin0(const float* __restrict__ x,
                                              const float* __restrict__ w0,
                                              const float* __restrict__ b0,
                                              float* __restrict__ F) {
    int lane = threadIdx.x & 63, wv = threadIdx.x >> 6;
    int n = blockIdx.x * 4 + wv;
    float xv = (lane < FIN) ? x[n * FIN + lane] : 0.f;
    float acc = b0[lane];
#pragma unroll
    for (int k = 0; k < FIN; ++k) acc += bcast(xv, k) * w0[k * 64 + lane];
    F[n * 64 + lane] = fmaxf(acc, 0.f);
}

// ---------------- gather: G[n][k*64+i] = sum_e hE[e][k]*F[src][i] (bf16 out) ----
__global__ __launch_bounds__(256) void k_gather(
    const float* __restrict__ F, const float* __restrict__ hE,
    const int* __restrict__ rowp, const int* __restrict__ csrs,
    const int* __restrict__ csre,
    ushort* __restrict__ GH, float* __restrict__ Usb) {
    int tid = threadIdx.x, lane = tid & 63, wv = tid >> 6;
    int n = __builtin_amdgcn_readfirstlane(blockIdx.x * 4 + wv);
    int beg = __builtin_amdgcn_readfirstlane(rowp[n]);
    int end = __builtin_amdgcn_readfirstlane(rowp[n + 1]);

    float G[64];
#pragma unroll
    for (int k = 0; k < 64; ++k) G[k] = 0.f;
    float usum = 0.f;
    {
        int p0 = beg + lane;
        int sl = (p0 < end) ? csrs[p0] : 0;
        int el = (p0 < end) ? csre[p0] : 0;
        int nb = min(end - beg, 64);
        for (int j = 0; j < nb; ++j) {
            int s = bcast_i(sl, j);
            int e = bcast_i(el, j);
            float u = F[(size_t)s * 64 + lane];
            float hv = hE[(size_t)e * 64 + lane];
            usum += u;
#pragma unroll
            for (int k = 0; k < 64; ++k) G[k] = fmaf(bcast(hv, k), u, G[k]);
        }
        for (int p = beg + 64; p < end; ++p) {  // deg>64: rare
            int s = __builtin_amdgcn_readfirstlane(csrs[p]);
            int e = __builtin_amdgcn_readfirstlane(csre[p]);
            float u = F[(size_t)s * 64 + lane];
            float hv = hE[(size_t)e * 64 + lane];
            usum += u;
#pragma unroll
            for (int k = 0; k < 64; ++k) G[k] = fmaf(bcast(hv, k), u, G[k]);
        }
    }
    Usb[(size_t)n * 64 + lane] = usum;
    ushort* gout = GH + (size_t)n * 4096 + lane;
#pragma unroll
    for (int k = 0; k < 64; ++k) gout[k * 64] = f2bf(G[k]);
}

// ---------------- contract: partial Agg = GH @ W2F^T (ki quarter) ----------------
// grid 2500 = 625 node-groups x 4 ki-quarters -> ~10 blocks/CU (R7 was 625
// blocks = 2.4/CU, pure latency-bound at 118us with all pipes <13% busy).
// Block (g,ks): 16 nodes, ki in [ks*1024,(ks+1)*1024), 2 LDS-staged chunks,
// partial D written to AggP[ks] (summed in fixed order by k_epi: no atomics,
// deterministic).
__global__ __launch_bounds__(256) void k_contract(
    const ushort* __restrict__ GH, const ushort* __restrict__ W2FH,
    const ushort* __restrict__ W2FL, float* __restrict__ AggP) {
    __shared__ __align__(16) ushort As[16 * 520];  // 16640 B
    int tid = threadIdx.x, lane = tid & 63, wv = tid >> 6;
    int g = blockIdx.x >> 2, ks = blockIdx.x & 3;
    int n0 = __builtin_amdgcn_readfirstlane(g * 16);
    int kbase = ks * 1024;
    int arow = lane & 15, agrp = lane >> 4;
    int o = wv * 16 + arow;
    const ushort* bh0 = W2FH + (size_t)o * 4096;
    const ushort* bl0 = W2FL + (size_t)o * 4096;

    f32x4 acc = {0.f, 0.f, 0.f, 0.f};
#pragma unroll
    for (int ch = 0; ch < 2; ++ch) {
        int c0 = kbase + ch * 512;
#pragma unroll
        for (int rep = 0; rep < 4; ++rep) {
            int off = rep * 2048 + tid * 8;
            int row = off >> 9, col = off & 511;
            *(s16x8*)&As[row * 520 + col] =
                *(const s16x8*)&GH[(size_t)(n0 + row) * 4096 + c0 + col];
        }
        __syncthreads();
#pragma unroll 4
        for (int s = 0; s < 16; ++s) {
            int kil = s * 32 + agrp * 8;
            s16x8 ah = *(const s16x8*)&As[arow * 520 + kil];
            s16x8 bh = *(const s16x8*)&bh0[c0 + kil];
            s16x8 bl = *(const s16x8*)&bl0[c0 + kil];
            acc = __builtin_amdgcn_mfma_f32_16x16x32_bf16(ah, bh, acc, 0, 0, 0);
            acc = __builtin_amdgcn_mfma_f32_16x16x32_bf16(ah, bl, acc, 0, 0, 0);
        }
        __syncthreads();
    }
    // partial D[row=node=agrp*4+r][col=o]
    float* ap = AggP + ((size_t)ks * NN + n0) * 64;
#pragma unroll
    for (int r = 0; r < 4; ++r)
        ap[(agrp * 4 + r) * 64 + o] = acc[r];
}

// ---------------- epilogue: sum partials + mean + nn2_b + root + GRU ----------------
// 625 blocks x 256 thr; wave = 4 nodes (weight rows amortized 4x).
__global__ __launch_bounds__(256) void k_epi(
    const float* __restrict__ AggP, const float* __restrict__ Usb,
    const float* __restrict__ B2, const float* __restrict__ invd,
    const float* __restrict__ F, const float* __restrict__ Wroot,
    const float* __restrict__ broot, const float* __restrict__ Wih,
    const float* __restrict__ Whh, const float* __restrict__ bih,
    const float* __restrict__ bhh, float* __restrict__ Fout) {
    int lane = threadIdx.x & 63, wv = threadIdx.x >> 6;
    int nq = blockIdx.x * 16 + wv * 4;

    float fv[4], uv[4], aa[4], rt[4], bt[4];
#pragma unroll
    for (int q = 0; q < 4; ++q) {
        size_t idx = (size_t)(nq + q) * 64 + lane;
        fv[q] = F[idx];
        uv[q] = Usb[idx];
        aa[q] = ((AggP[idx] + AggP[(size_t)NN * 64 + idx]) +
                 AggP[(size_t)2 * NN * 64 + idx]) +
                AggP[(size_t)3 * NN * 64 + idx];
        rt[q] = broot[lane];
        bt[q] = 0.f;
    }
#pragma unroll 8
    for (int k = 0; k < 64; ++k) {
        float wr = Wroot[k * 64 + lane];
        float b2 = B2[k * 64 + lane];
#pragma unroll
        for (int q = 0; q < 4; ++q) {
            rt[q] = fmaf(bcast(fv[q], k), wr, rt[q]);
            bt[q] = fmaf(bcast(uv[q], k), b2, bt[q]);
        }
    }
    float m[4];
#pragma unroll
    for (int q = 0; q < 4; ++q)
        m[q] = fmaxf((aa[q] + bt[q]) * invd[nq + q] + rt[q], 0.f);

    float sr[4], sz[4], gn[4], gh[4];
#pragma unroll
    for (int q = 0; q < 4; ++q) {
        sr[q] = bih[lane] + bhh[lane];
        sz[q] = bih[64 + lane] + bhh[64 + lane];
        gn[q] = bih[128 + lane];
        gh[q] = bhh[128 + lane];
    }
#pragma unroll 8
    for (int k = 0; k < 64; ++k) {
        float wi0 = Wih[k * 192 + lane];
        float wi1 = Wih[k * 192 + 64 + lane];
        float wi2 = Wih[k * 192 + 128 + lane];
        float wh0 = Whh[k * 192 + lane];
        float wh1 = Whh[k * 192 + 64 + lane];
        float wh2 = Whh[k * 192 + 128 + lane];
#pragma unroll
        for (int q = 0; q < 4; ++q) {
            float mk = bcast(m[q], k), hk = bcast(fv[q], k);
            sr[q] = fmaf(mk, wi0, fmaf(hk, wh0, sr[q]));
            sz[q] = fmaf(mk, wi1, fmaf(hk, wh1, sz[q]));
            gn[q] = fmaf(mk, wi2, gn[q]);
            gh[q] = fmaf(hk, wh2, gh[q]);
        }
    }
#pragma unroll
    for (int q = 0; q < 4; ++q) {
        float rr = 1.f / (1.f + __expf(-sr[q]));
        float zz = 1.f / (1.f + __expf(-sz[q]));
        float ng = tanhf(gn[q] + rr * gh[q]);
        Fout[(size_t)(nq + q) * 64 + lane] = (1.f - zz) * ng + zz * fv[q];
    }
}

// ---------------- final ----------------
__global__ __launch_bounds__(256) void k_final(const float* __restrict__ F,
                                               const float* __restrict__ W1,
                                               const float* __restrict__ b1f,
                                               const float* __restrict__ W2l,
                                               const float* __restrict__ b2f,
                                               float* __restrict__ out) {
    int lane = threadIdx.x & 63, wv = threadIdx.x >> 6;
    int n = blockIdx.x * 4 + wv;
    float fv = F[n * 64 + lane];
    float acc = b1f[lane];
#pragma unroll
    for (int k = 0; k < 64; ++k) acc += bcast(fv, k) * W1[k * 64 + lane];
    acc = fmaxf(acc, 0.f);
    float p = acc * W2l[lane];
#pragma unroll
    for (int off = 32; off; off >>= 1) p += __shfl_xor(p, off, 64);
    if (lane == 0) out[n] = p + b2f[0];
}

extern "C" void kernel_launch(void* const* d_in, const int* in_sizes, int n_in,
                              void* d_out, int out_size, void* d_ws, size_t ws_size,
                              hipStream_t stream) {
    const float* x = (const float*)d_in[0];
    const int* ei = (const int*)d_in[1];
    const float* ea = (const float*)d_in[2];
    const float* l0w = (const float*)d_in[3];
    const float* l0b = (const float*)d_in[4];
    const float* n1w = (const float*)d_in[5];
    const float* n1b = (const float*)d_in[6];
    const float* n2w = (const float*)d_in[7];
    const float* n2b = (const float*)d_in[8];
    const float* cr = (const float*)d_in[9];
    const float* cb = (const float*)d_in[10];
    const float* wih = (const float*)d_in[11];
    const float* whh = (const float*)d_in[12];
    const float* bih = (const float*)d_in[13];
    const float* bhh = (const float*)d_in[14];
    const float* l1w = (const float*)d_in[15];
    const float* l1b = (const float*)d_in[16];
    const float* l2w = (const float*)d_in[17];
    const float* l2b = (const float*)d_in[18];

    char* w = (char*)d_ws;
    size_t off = 0;
    float* F0 = (float*)(w + off); off += (size_t)NN * 64 * 4;
    float* F1 = (float*)(w + off); off += (size_t)NN * 64 * 4;
    float* hE = (float*)(w + off); off += (size_t)NE * 64 * 4;
    ushort* W2FH = (ushort*)(w + off); off += (size_t)64 * 4096 * 2;
    ushort* W2FL = (ushort*)(w + off); off += (size_t)64 * 4096 * 2;
    ushort* GH = (ushort*)(w + off); off += (size_t)NN * 4096 * 2;   // 80 MB
    float* AggP = (float*)(w + off); off += (size_t)4 * NN * 64 * 4; // 10 MB
    float* Usb = (float*)(w + off); off += (size_t)NN * 64 * 4;      // 2.5 MB
    float* invd = (float*)(w + off); off += (size_t)NN * 4;
    int* deg = (int*)(w + off); off += (size_t)NN * 4;
    int* rowp = (int*)(w + off); off += (size_t)(NN + 1) * 4 + 252; off &= ~(size_t)255;
    int* fill = (int*)(w + off); off += (size_t)NN * 4;
    int* csrs = (int*)(w + off); off += (size_t)NE * 4;
    int* csre = (int*)(w + off); off += (size_t)NE * 4;

    hipMemsetAsync(deg, 0, NN * 4, stream);
    k_count<<<(NE + 255) / 256, 256, 0, stream>>>(ei, deg);
    k_scan<<<1, 1024, 0, stream>>>(deg, rowp, fill, invd);
    k_fill<<<(NE + 255) / 256, 256, 0, stream>>>(ei, fill, csrs, csre);
    k_w2f<<<1024, 256, 0, stream>>>(n2w, W2FH, W2FL);
    k_edge_h<<<NE / 4, 256, 0, stream>>>(ea, n1w, n1b, hE);
    k_lin0<<<NN / 4, 256, 0, stream>>>(x, l0w, l0b, F0);
    float* Fcur = F0;
    float* Fnxt = F1;
    for (int it = 0; it < 3; ++it) {
        k_gather<<<NN / 4, 256, 0, stream>>>(Fcur, hE, rowp, csrs, csre, GH, Usb);
        k_contract<<<(NN / 16) * 4, 256, 0, stream>>>(GH, W2FH, W2FL, AggP);
        k_epi<<<NN / 16, 256, 0, stream>>>(AggP, Usb, n2b, invd, Fcur, cr, cb,
                                           wih, whh, bih, bhh, Fnxt);
        float* t = Fcur; Fcur = Fnxt; Fnxt = t;
    }
    k_final<<<NN / 4, 256, 0, stream>>>(Fcur, l1w, l1b, l2w, l2b, (float*)d_out);
}

// Round 10
// 377.766 us; speedup vs baseline: 1.7848x; 1.1948x over previous
//
#include <hip/hip_runtime.h>
#include <hip/hip_bf16.h>

#define NN 10000
#define NP 10016  // GH rows padded to 32-node groups
#define NE 50000
#define FIN 40
#define FE 10
// L = 64

typedef float f32x4 __attribute__((ext_vector_type(4)));
typedef short s16x8 __attribute__((ext_vector_type(8)));

__device__ __forceinline__ float bcast(float v, int lane) {
    return __uint_as_float(__builtin_amdgcn_readlane(__float_as_uint(v), lane));
}
__device__ __forceinline__ int bcast_i(int v, int lane) {
    return __builtin_amdgcn_readlane(v, lane);
}
__device__ __forceinline__ ushort f2bf(float f) {
    uint u = __float_as_uint(f);
    uint r = (u + 0x7FFFu + ((u >> 16) & 1u)) >> 16;
    return (ushort)r;
}
__device__ __forceinline__ float bf2f(ushort h) {
    return __uint_as_float(((uint)h) << 16);
}

// ---------------- CSR build ----------------
__global__ void k_count(const int* __restrict__ ei, int* __restrict__ deg) {
    int e = blockIdx.x * 256 + threadIdx.x;
    if (e < NE) atomicAdd(&deg[ei[NE + e]], 1);
}

__global__ __launch_bounds__(1024) void k_scan(const int* __restrict__ deg,
                                               int* __restrict__ rowp,
                                               int* __restrict__ fill,
                                               float* __restrict__ invd) {
    __shared__ int wsum[16];
    __shared__ int chunkbase;
    int tid = threadIdx.x, lane = tid & 63, wv = tid >> 6;
    if (tid == 0) chunkbase = 0;
    __syncthreads();
    for (int base = 0; base < NN; base += 1024) {
        int idx = base + tid;
        int v = (idx < NN) ? deg[idx] : 0;
        int s = v;
#pragma unroll
        for (int off = 1; off < 64; off <<= 1) {
            int t = __shfl_up(s, off, 64);
            if (lane >= off) s += t;
        }
        if (lane == 63) wsum[wv] = s;
        __syncthreads();
        int carry = chunkbase;
        if (wv == 0 && lane < 16) {
            int x = wsum[lane];
#pragma unroll
            for (int off = 1; off < 16; off <<= 1) {
                int t = __shfl_up(x, off, 64);
                if (lane >= off) x += t;
            }
            wsum[lane] = x;  // inclusive over waves
        }
        __syncthreads();
        int wpre = (wv == 0) ? 0 : wsum[wv - 1];
        int incl = carry + wpre + s;
        if (idx < NN) {
            rowp[idx] = incl - v;
            fill[idx] = incl - v;
            invd[idx] = 1.0f / (float)(v > 0 ? v : 1);
        }
        __syncthreads();
        if (tid == 0) chunkbase = carry + wsum[15];
        __syncthreads();
    }
    if (tid == 0) rowp[NN] = NE;
}

__global__ void k_fill(const int* __restrict__ ei, int* __restrict__ fill,
                       int* __restrict__ csrs, int* __restrict__ csre) {
    int e = blockIdx.x * 256 + threadIdx.x;
    if (e < NE) {
        int d = ei[NE + e];
        int p = atomicAdd(&fill[d], 1);
        csrs[p] = ei[e];
        csre[p] = e;
    }
}

// ---------------- W2 split-bf16, transposed to [o][ki] (ki = k*64+i) ----------------
__global__ __launch_bounds__(256) void k_w2f(const float* __restrict__ n2w,
                                             ushort* __restrict__ W2FH,
                                             ushort* __restrict__ W2FL) {
    int lane = threadIdx.x & 63, wvl = threadIdx.x >> 6;
    int ki = blockIdx.x * 4 + wvl;
    float v = n2w[(size_t)ki * 64 + lane];
    ushort hi = f2bf(v);
    ushort lo = f2bf(v - bf2f(hi));
    W2FH[(size_t)lane * 4096 + ki] = hi;
    W2FL[(size_t)lane * 4096 + ki] = lo;
}

// ---------------- edge MLP: hE = relu(edge_attr @ nn1_w + nn1_b) ----------------
__global__ __launch_bounds__(256) void k_edge_h(const float* __restrict__ ea,
                                                const float* __restrict__ w1,
                                                const float* __restrict__ b1,
                                                float* __restrict__ hE) {
    int lane = threadIdx.x & 63, wv = threadIdx.x >> 6;
    int e = blockIdx.x * 4 + wv;
    float av = (lane < FE) ? ea[e * FE + lane] : 0.f;
    float acc = b1[lane];
#pragma unroll
    for (int j = 0; j < FE; ++j) acc += bcast(av, j) * w1[j * 64 + lane];
    hE[e * 64 + lane] = fmaxf(acc, 0.f);
}

// ---------------- lin0 ----------------
__global__ __launch_bounds__(256) void k_lin0(const float* __restrict__ x,
                                              const float* __restrict__ w0,
                                              const float* __restrict__ b0,
                                              float* __restrict__ F) {
    int lane = threadIdx.x & 63, wv = threadIdx.x >> 6;
    int n = blockIdx.x * 4 + wv;
    float xv = (lane < FIN) ? x[n * FIN + lane] : 0.f;
    float acc = b0[lane];
#pragma unroll
    for (int k = 0; k < FIN; ++k) acc += bcast(xv, k) * w0[k * 64 + lane];
    F[n * 64 + lane] = fmaxf(acc, 0.f);
}

// ---------------- gather: G[n][k*64+i] = sum_e hE[e][k]*F[src][i] (bf16 out) ----
__global__ __launch_bounds__(256) void k_gather(
    const float* __restrict__ F, const float* __restrict__ hE,
    const int* __restrict__ rowp, const int* __restrict__ csrs,
    const int* __restrict__ csre,
    ushort* __restrict__ GH, float* __restrict__ Usb) {
    int tid = threadIdx.x, lane = tid & 63, wv = tid >> 6;
    int n = __builtin_amdgcn_readfirstlane(blockIdx.x * 4 + wv);
    int beg = __builtin_amdgcn_readfirstlane(rowp[n]);
    int end = __builtin_amdgcn_readfirstlane(rowp[n + 1]);

    float G[64];
#pragma unroll
    for (int k = 0; k < 64; ++k) G[k] = 0.f;
    float usum = 0.f;
    {
        int p0 = beg + lane;
        int sl = (p0 < end) ? csrs[p0] : 0;
        int el = (p0 < end) ? csre[p0] : 0;
        int nb = min(end - beg, 64);
        for (int j = 0; j < nb; ++j) {
            int s = bcast_i(sl, j);
            int e = bcast_i(el, j);
            float u = F[(size_t)s * 64 + lane];
            float hv = hE[(size_t)e * 64 + lane];
            usum += u;
#pragma unroll
            for (int k = 0; k < 64; ++k) G[k] = fmaf(bcast(hv, k), u, G[k]);
        }
        for (int p = beg + 64; p < end; ++p) {  // deg>64: rare
            int s = __builtin_amdgcn_readfirstlane(csrs[p]);
            int e = __builtin_amdgcn_readfirstlane(csre[p]);
            float u = F[(size_t)s * 64 + lane];
            float hv = hE[(size_t)e * 64 + lane];
            usum += u;
#pragma unroll
            for (int k = 0; k < 64; ++k) G[k] = fmaf(bcast(hv, k), u, G[k]);
        }
    }
    Usb[(size_t)n * 64 + lane] = usum;
    ushort* gout = GH + (size_t)n * 4096 + lane;
#pragma unroll
    for (int k = 0; k < 64; ++k) gout[k * 64] = f2bf(G[k]);
}

// ---------------- contract: partial Agg = GH @ W2F^T (ki quarter) ----------------
// Block (g, ks): 32 nodes (two 16-row MFMA tiles -> 2 independent acc chains
// sharing every B-load: 2x B amortization + 2-way MFMA ILP vs R8, whose
// counters showed 93% memory-stall with all pipes idle), ki quarter of 1024.
// Grid 313*4 = 1252; LDS 33 KB -> 4 blocks/CU. Tail group: guarded stores
// (D rows are independent; GH is padded to NP rows so staging stays in-bounds).
__global__ __launch_bounds__(256) void k_contract(
    const ushort* __restrict__ GH, const ushort* __restrict__ W2FH,
    const ushort* __restrict__ W2FL, float* __restrict__ AggP) {
    __shared__ __align__(16) ushort As[32 * 520];  // 33280 B
    int tid = threadIdx.x, lane = tid & 63, wv = tid >> 6;
    int g = blockIdx.x >> 2, ks = blockIdx.x & 3;
    int n0 = __builtin_amdgcn_readfirstlane(g * 32);
    int kbase = ks * 1024;
    int arow = lane & 15, agrp = lane >> 4;
    int o = wv * 16 + arow;
    const ushort* bh0 = W2FH + (size_t)o * 4096;
    const ushort* bl0 = W2FL + (size_t)o * 4096;

    f32x4 acc0 = {0.f, 0.f, 0.f, 0.f};
    f32x4 acc1 = {0.f, 0.f, 0.f, 0.f};
#pragma unroll
    for (int ch = 0; ch < 2; ++ch) {
        int c0 = kbase + ch * 512;
#pragma unroll
        for (int rep = 0; rep < 8; ++rep) {
            int off = rep * 2048 + tid * 8;
            int row = off >> 9, col = off & 511;
            *(s16x8*)&As[row * 520 + col] =
                *(const s16x8*)&GH[(size_t)(n0 + row) * 4096 + c0 + col];
        }
        __syncthreads();
#pragma unroll 4
        for (int s = 0; s < 16; ++s) {
            int kil = s * 32 + agrp * 8;
            s16x8 bh = *(const s16x8*)&bh0[c0 + kil];
            s16x8 bl = *(const s16x8*)&bl0[c0 + kil];
            s16x8 a0 = *(const s16x8*)&As[arow * 520 + kil];
            s16x8 a1 = *(const s16x8*)&As[(16 + arow) * 520 + kil];
            acc0 = __builtin_amdgcn_mfma_f32_16x16x32_bf16(a0, bh, acc0, 0, 0, 0);
            acc1 = __builtin_amdgcn_mfma_f32_16x16x32_bf16(a1, bh, acc1, 0, 0, 0);
            acc0 = __builtin_amdgcn_mfma_f32_16x16x32_bf16(a0, bl, acc0, 0, 0, 0);
            acc1 = __builtin_amdgcn_mfma_f32_16x16x32_bf16(a1, bl, acc1, 0, 0, 0);
        }
        __syncthreads();
    }
    // partial D[row][col=o]; row r of tile t -> node n0 + t*16 + agrp*4 + r
    float* ap = AggP + ((size_t)ks * NN + n0) * 64;
#pragma unroll
    for (int r = 0; r < 4; ++r) {
        int row0 = agrp * 4 + r;
        if (n0 + row0 < NN) ap[row0 * 64 + o] = acc0[r];
        int row1 = 16 + agrp * 4 + r;
        if (n0 + row1 < NN) ap[row1 * 64 + o] = acc1[r];
    }
}

// ---------------- epilogue: sum partials + mean + nn2_b + root + GRU ----------------
__global__ __launch_bounds__(256) void k_epi(
    const float* __restrict__ AggP, const float* __restrict__ Usb,
    const float* __restrict__ B2, const float* __restrict__ invd,
    const float* __restrict__ F, const float* __restrict__ Wroot,
    const float* __restrict__ broot, const float* __restrict__ Wih,
    const float* __restrict__ Whh, const float* __restrict__ bih,
    const float* __restrict__ bhh, float* __restrict__ Fout) {
    int lane = threadIdx.x & 63, wv = threadIdx.x >> 6;
    int nq = blockIdx.x * 16 + wv * 4;

    float fv[4], uv[4], aa[4], rt[4], bt[4];
#pragma unroll
    for (int q = 0; q < 4; ++q) {
        size_t idx = (size_t)(nq + q) * 64 + lane;
        fv[q] = F[idx];
        uv[q] = Usb[idx];
        aa[q] = ((AggP[idx] + AggP[(size_t)NN * 64 + idx]) +
                 AggP[(size_t)2 * NN * 64 + idx]) +
                AggP[(size_t)3 * NN * 64 + idx];
        rt[q] = broot[lane];
        bt[q] = 0.f;
    }
#pragma unroll 8
    for (int k = 0; k < 64; ++k) {
        float wr = Wroot[k * 64 + lane];
        float b2 = B2[k * 64 + lane];
#pragma unroll
        for (int q = 0; q < 4; ++q) {
            rt[q] = fmaf(bcast(fv[q], k), wr, rt[q]);
            bt[q] = fmaf(bcast(uv[q], k), b2, bt[q]);
        }
    }
    float m[4];
#pragma unroll
    for (int q = 0; q < 4; ++q)
        m[q] = fmaxf((aa[q] + bt[q]) * invd[nq + q] + rt[q], 0.f);

    float sr[4], sz[4], gn[4], gh[4];
#pragma unroll
    for (int q = 0; q < 4; ++q) {
        sr[q] = bih[lane] + bhh[lane];
        sz[q] = bih[64 + lane] + bhh[64 + lane];
        gn[q] = bih[128 + lane];
        gh[q] = bhh[128 + lane];
    }
#pragma unroll 8
    for (int k = 0; k < 64; ++k) {
        float wi0 = Wih[k * 192 + lane];
        float wi1 = Wih[k * 192 + 64 + lane];
        float wi2 = Wih[k * 192 + 128 + lane];
        float wh0 = Whh[k * 192 + lane];
        float wh1 = Whh[k * 192 + 64 + lane];
        float wh2 = Whh[k * 192 + 128 + lane];
#pragma unroll
        for (int q = 0; q < 4; ++q) {
            float mk = bcast(m[q], k), hk = bcast(fv[q], k);
            sr[q] = fmaf(mk, wi0, fmaf(hk, wh0, sr[q]));
            sz[q] = fmaf(mk, wi1, fmaf(hk, wh1, sz[q]));
            gn[q] = fmaf(mk, wi2, gn[q]);
            gh[q] = fmaf(hk, wh2, gh[q]);
        }
    }
#pragma unroll
    for (int q = 0; q < 4; ++q) {
        float rr = 1.f / (1.f + __expf(-sr[q]));
        float zz = 1.f / (1.f + __expf(-sz[q]));
        float ng = tanhf(gn[q] + rr * gh[q]);
        Fout[(size_t)(nq + q) * 64 + lane] = (1.f - zz) * ng + zz * fv[q];
    }
}

// ---------------- final ----------------
__global__ __launch_bounds__(256) void k_final(const float* __restrict__ F,
                                               const float* __restrict__ W1,
                                               const float* __restrict__ b1f,
                                               const float* __restrict__ W2l,
                                               const float* __restrict__ b2f,
                                               float* __restrict__ out) {
    int lane = threadIdx.x & 63, wv = threadIdx.x >> 6;
    int n = blockIdx.x * 4 + wv;
    float fv = F[n * 64 + lane];
    float acc = b1f[lane];
#pragma unroll
    for (int k = 0; k < 64; ++k) acc += bcast(fv, k) * W1[k * 64 + lane];
    acc = fmaxf(acc, 0.f);
    float p = acc * W2l[lane];
#pragma unroll
    for (int off = 32; off; off >>= 1) p += __shfl_xor(p, off, 64);
    if (lane == 0) out[n] = p + b2f[0];
}

extern "C" void kernel_launch(void* const* d_in, const int* in_sizes, int n_in,
                              void* d_out, int out_size, void* d_ws, size_t ws_size,
                              hipStream_t stream) {
    const float* x = (const float*)d_in[0];
    const int* ei = (const int*)d_in[1];
    const float* ea = (const float*)d_in[2];
    const float* l0w = (const float*)d_in[3];
    const float* l0b = (const float*)d_in[4];
    const float* n1w = (const float*)d_in[5];
    const float* n1b = (const float*)d_in[6];
    const float* n2w = (const float*)d_in[7];
    const float* n2b = (const float*)d_in[8];
    const float* cr = (const float*)d_in[9];
    const float* cb = (const float*)d_in[10];
    const float* wih = (const float*)d_in[11];
    const float* whh = (const float*)d_in[12];
    const float* bih = (const float*)d_in[13];
    const float* bhh = (const float*)d_in[14];
    const float* l1w = (const float*)d_in[15];
    const float* l1b = (const float*)d_in[16];
    const float* l2w = (const float*)d_in[17];
    const float* l2b = (const float*)d_in[18];

    char* w = (char*)d_ws;
    size_t off = 0;
    float* F0 = (float*)(w + off); off += (size_t)NN * 64 * 4;
    float* F1 = (float*)(w + off); off += (size_t)NN * 64 * 4;
    float* hE = (float*)(w + off); off += (size_t)NE * 64 * 4;
    ushort* W2FH = (ushort*)(w + off); off += (size_t)64 * 4096 * 2;
    ushort* W2FL = (ushort*)(w + off); off += (size_t)64 * 4096 * 2;
    ushort* GH = (ushort*)(w + off); off += (size_t)NP * 4096 * 2;   // 82 MB
    float* AggP = (float*)(w + off); off += (size_t)4 * NN * 64 * 4; // 10 MB
    float* Usb = (float*)(w + off); off += (size_t)NN * 64 * 4;      // 2.5 MB
    float* invd = (float*)(w + off); off += (size_t)NN * 4;
    int* deg = (int*)(w + off); off += (size_t)NN * 4;
    int* rowp = (int*)(w + off); off += (size_t)(NN + 1) * 4 + 252; off &= ~(size_t)255;
    int* fill = (int*)(w + off); off += (size_t)NN * 4;
    int* csrs = (int*)(w + off); off += (size_t)NE * 4;
    int* csre = (int*)(w + off); off += (size_t)NE * 4;

    hipMemsetAsync(deg, 0, NN * 4, stream);
    k_count<<<(NE + 255) / 256, 256, 0, stream>>>(ei, deg);
    k_scan<<<1, 1024, 0, stream>>>(deg, rowp, fill, invd);
    k_fill<<<(NE + 255) / 256, 256, 0, stream>>>(ei, fill, csrs, csre);
    k_w2f<<<1024, 256, 0, stream>>>(n2w, W2FH, W2FL);
    k_edge_h<<<NE / 4, 256, 0, stream>>>(ea, n1w, n1b, hE);
    k_lin0<<<NN / 4, 256, 0, stream>>>(x, l0w, l0b, F0);
    float* Fcur = F0;
    float* Fnxt = F1;
    for (int it = 0; it < 3; ++it) {
        k_gather<<<NN / 4, 256, 0, stream>>>(Fcur, hE, rowp, csrs, csre, GH, Usb);
        k_contract<<<((NN + 31) / 32) * 4, 256, 0, stream>>>(GH, W2FH, W2FL, AggP);
        k_epi<<<NN / 16, 256, 0, stream>>>(AggP, Usb, n2b, invd, Fcur, cr, cb,
                                           wih, whh, bih, bhh, Fnxt);
        float* t = Fcur; Fcur = Fnxt; Fnxt = t;
    }
    k_final<<<NN / 4, 256, 0, stream>>>(Fcur, l1w, l1b, l2w, l2b, (float*)d_out);
}

// Round 11
// 323.099 us; speedup vs baseline: 2.0868x; 1.1692x over previous
//
#include <hip/hip_runtime.h>
#include <hip/hip_bf16.h>

#define NN 10000
#define NP 10016  // GH rows padded to 16-node groups (626 m-groups)
#define NE 50000
#define FIN 40
#define FE 10
#define MCH 20    // m-groups per contract chunk (last chunk = 6)
// L = 64

typedef float f32x4 __attribute__((ext_vector_type(4)));
typedef short s16x8 __attribute__((ext_vector_type(8)));

__device__ __forceinline__ float bcast(float v, int lane) {
    return __uint_as_float(__builtin_amdgcn_readlane(__float_as_uint(v), lane));
}
__device__ __forceinline__ int bcast_i(int v, int lane) {
    return __builtin_amdgcn_readlane(v, lane);
}
__device__ __forceinline__ ushort f2bf(float f) {
    uint u = __float_as_uint(f);
    uint r = (u + 0x7FFFu + ((u >> 16) & 1u)) >> 16;
    return (ushort)r;
}
__device__ __forceinline__ float bf2f(ushort h) {
    return __uint_as_float(((uint)h) << 16);
}

// ---------------- CSR build ----------------
__global__ void k_count(const int* __restrict__ ei, int* __restrict__ deg) {
    int e = blockIdx.x * 256 + threadIdx.x;
    if (e < NE) atomicAdd(&deg[ei[NE + e]], 1);
}

__global__ __launch_bounds__(1024) void k_scan(const int* __restrict__ deg,
                                               int* __restrict__ rowp,
                                               int* __restrict__ fill,
                                               float* __restrict__ invd) {
    __shared__ int wsum[16];
    __shared__ int chunkbase;
    int tid = threadIdx.x, lane = tid & 63, wv = tid >> 6;
    if (tid == 0) chunkbase = 0;
    __syncthreads();
    for (int base = 0; base < NN; base += 1024) {
        int idx = base + tid;
        int v = (idx < NN) ? deg[idx] : 0;
        int s = v;
#pragma unroll
        for (int off = 1; off < 64; off <<= 1) {
            int t = __shfl_up(s, off, 64);
            if (lane >= off) s += t;
        }
        if (lane == 63) wsum[wv] = s;
        __syncthreads();
        int carry = chunkbase;
        if (wv == 0 && lane < 16) {
            int x = wsum[lane];
#pragma unroll
            for (int off = 1; off < 16; off <<= 1) {
                int t = __shfl_up(x, off, 64);
                if (lane >= off) x += t;
            }
            wsum[lane] = x;  // inclusive over waves
        }
        __syncthreads();
        int wpre = (wv == 0) ? 0 : wsum[wv - 1];
        int incl = carry + wpre + s;
        if (idx < NN) {
            rowp[idx] = incl - v;
            fill[idx] = incl - v;
            invd[idx] = 1.0f / (float)(v > 0 ? v : 1);
        }
        __syncthreads();
        if (tid == 0) chunkbase = carry + wsum[15];
        __syncthreads();
    }
    if (tid == 0) rowp[NN] = NE;
}

__global__ void k_fill(const int* __restrict__ ei, int* __restrict__ fill,
                       int* __restrict__ csrs, int* __restrict__ csre) {
    int e = blockIdx.x * 256 + threadIdx.x;
    if (e < NE) {
        int d = ei[NE + e];
        int p = atomicAdd(&fill[d], 1);
        csrs[p] = ei[e];
        csre[p] = e;
    }
}

// ---------------- W2 split-bf16, transposed to [o][ki] (ki = k*64+i) ----------------
__global__ __launch_bounds__(256) void k_w2f(const float* __restrict__ n2w,
                                             ushort* __restrict__ W2FH,
                                             ushort* __restrict__ W2FL) {
    int lane = threadIdx.x & 63, wvl = threadIdx.x >> 6;
    int ki = blockIdx.x * 4 + wvl;
    float v = n2w[(size_t)ki * 64 + lane];
    ushort hi = f2bf(v);
    ushort lo = f2bf(v - bf2f(hi));
    W2FH[(size_t)lane * 4096 + ki] = hi;
    W2FL[(size_t)lane * 4096 + ki] = lo;
}

// ---------------- edge MLP: hE = relu(edge_attr @ nn1_w + nn1_b) ----------------
__global__ __launch_bounds__(256) void k_edge_h(const float* __restrict__ ea,
                                                const float* __restrict__ w1,
                                                const float* __restrict__ b1,
                                                float* __restrict__ hE) {
    int lane = threadIdx.x & 63, wv = threadIdx.x >> 6;
    int e = blockIdx.x * 4 + wv;
    float av = (lane < FE) ? ea[e * FE + lane] : 0.f;
    float acc = b1[lane];
#pragma unroll
    for (int j = 0; j < FE; ++j) acc += bcast(av, j) * w1[j * 64 + lane];
    hE[e * 64 + lane] = fmaxf(acc, 0.f);
}

// ---------------- lin0 ----------------
__global__ __launch_bounds__(256) void k_lin0(const float* __restrict__ x,
                                              const float* __restrict__ w0,
                                              const float* __restrict__ b0,
                                              float* __restrict__ F) {
    int lane = threadIdx.x & 63, wv = threadIdx.x >> 6;
    int n = blockIdx.x * 4 + wv;
    float xv = (lane < FIN) ? x[n * FIN + lane] : 0.f;
    float acc = b0[lane];
#pragma unroll
    for (int k = 0; k < FIN; ++k) acc += bcast(xv, k) * w0[k * 64 + lane];
    F[n * 64 + lane] = fmaxf(acc, 0.f);
}

// ---------------- gather: G[n][k*64+i] = sum_e hE[e][k]*F[src][i] (bf16 out) ----
__global__ __launch_bounds__(256) void k_gather(
    const float* __restrict__ F, const float* __restrict__ hE,
    const int* __restrict__ rowp, const int* __restrict__ csrs,
    const int* __restrict__ csre,
    ushort* __restrict__ GH, float* __restrict__ Usb) {
    int tid = threadIdx.x, lane = tid & 63, wv = tid >> 6;
    int n = __builtin_amdgcn_readfirstlane(blockIdx.x * 4 + wv);
    int beg = __builtin_amdgcn_readfirstlane(rowp[n]);
    int end = __builtin_amdgcn_readfirstlane(rowp[n + 1]);

    float G[64];
#pragma unroll
    for (int k = 0; k < 64; ++k) G[k] = 0.f;
    float usum = 0.f;
    {
        int p0 = beg + lane;
        int sl = (p0 < end) ? csrs[p0] : 0;
        int el = (p0 < end) ? csre[p0] : 0;
        int nb = min(end - beg, 64);
        for (int j = 0; j < nb; ++j) {
            int s = bcast_i(sl, j);
            int e = bcast_i(el, j);
            float u = F[(size_t)s * 64 + lane];
            float hv = hE[(size_t)e * 64 + lane];
            usum += u;
#pragma unroll
            for (int k = 0; k < 64; ++k) G[k] = fmaf(bcast(hv, k), u, G[k]);
        }
        for (int p = beg + 64; p < end; ++p) {  // deg>64: rare
            int s = __builtin_amdgcn_readfirstlane(csrs[p]);
            int e = __builtin_amdgcn_readfirstlane(csre[p]);
            float u = F[(size_t)s * 64 + lane];
            float hv = hE[(size_t)e * 64 + lane];
            usum += u;
#pragma unroll
            for (int k = 0; k < 64; ++k) G[k] = fmaf(bcast(hv, k), u, G[k]);
        }
    }
    Usb[(size_t)n * 64 + lane] = usum;
    ushort* gout = GH + (size_t)n * 4096 + lane;
#pragma unroll
    for (int k = 0; k < 64; ++k) gout[k * 64] = f2bf(G[k]);
}

// ---------------- contract v3: B-stationary GEMM ----------------
// AggP[ks] += GH(m-chunk) @ W2F(ki-eighth)^T. Grid 32 m-chunks x 8 ki-eighths
// = 256 blocks (1/CU), 512 thr = 8 waves (4 o-tiles x 2 m-halves).
// B eighth (64 o x 512 ki, hi+lo) staged ONCE in 130 KB LDS (B L2 traffic
// 320 MB -> 33 MB vs R9); A streamed per-lane global->VGPR, no barriers in
// the main loop. 2 independent acc chains/wave (m-group pair shares every
// B ds_read) -> ~4 MFMA chains/SIMD. Partials summed in k_epi (fixed order).
__global__ __launch_bounds__(512) void k_contract(
    const ushort* __restrict__ GH, const ushort* __restrict__ W2FH,
    const ushort* __restrict__ W2FL, float* __restrict__ AggP) {
    __shared__ __align__(16) ushort BH[64 * 520];  // 66560 B
    __shared__ __align__(16) ushort BL[64 * 520];  // 66560 B
    int tid = threadIdx.x, lane = tid & 63, wv = tid >> 6;
    int ks = blockIdx.x & 7;   // ki eighth
    int mc = blockIdx.x >> 3;  // m chunk 0..31
    int kbase = ks * 512;
    int otile = wv & 3, mhalf = wv >> 2;
    int arow = lane & 15, agrp = lane >> 4;
    int o = otile * 16 + arow;

    // ---- stage B (coalesced): 8 reps x 512thr x 8 ushort ----
#pragma unroll
    for (int rep = 0; rep < 8; ++rep) {
        int off = rep * 4096 + tid * 8;
        int row = off >> 9, col = off & 511;
        *(s16x8*)&BH[row * 520 + col] =
            *(const s16x8*)&W2FH[(size_t)row * 4096 + kbase + col];
        *(s16x8*)&BL[row * 520 + col] =
            *(const s16x8*)&W2FL[(size_t)row * 4096 + kbase + col];
    }
    __syncthreads();

    int mg0 = mc * MCH;
    int mgend = min(mg0 + MCH, NP / 16);
    float* ap = AggP + (size_t)ks * NN * 64;
    for (int mg = mg0 + mhalf * 2; mg < mgend; mg += 4) {
        const ushort* pA = GH + (size_t)(mg * 16 + arow) * 4096 + kbase;
        const ushort* pB = GH + (size_t)((mg + 1) * 16 + arow) * 4096 + kbase;
        f32x4 acc0 = {0.f, 0.f, 0.f, 0.f};
        f32x4 acc1 = {0.f, 0.f, 0.f, 0.f};
#pragma unroll 4
        for (int s = 0; s < 16; ++s) {
            int kil = s * 32 + agrp * 8;
            s16x8 a0 = *(const s16x8*)&pA[kil];
            s16x8 a1 = *(const s16x8*)&pB[kil];
            s16x8 bh = *(const s16x8*)&BH[o * 520 + kil];
            s16x8 bl = *(const s16x8*)&BL[o * 520 + kil];
            acc0 = __builtin_amdgcn_mfma_f32_16x16x32_bf16(a0, bh, acc0, 0, 0, 0);
            acc1 = __builtin_amdgcn_mfma_f32_16x16x32_bf16(a1, bh, acc1, 0, 0, 0);
            acc0 = __builtin_amdgcn_mfma_f32_16x16x32_bf16(a0, bl, acc0, 0, 0, 0);
            acc1 = __builtin_amdgcn_mfma_f32_16x16x32_bf16(a1, bl, acc1, 0, 0, 0);
        }
        // D row r of tile -> node mg*16 + agrp*4 + r
#pragma unroll
        for (int r = 0; r < 4; ++r) {
            int n0r = mg * 16 + agrp * 4 + r;
            if (n0r < NN) ap[(size_t)n0r * 64 + o] = acc0[r];
            int n1r = (mg + 1) * 16 + agrp * 4 + r;
            if (n1r < NN) ap[(size_t)n1r * 64 + o] = acc1[r];
        }
    }
}

// ---------------- epilogue: sum 8 partials + mean + nn2_b + root + GRU ----------------
__global__ __launch_bounds__(256) void k_epi(
    const float* __restrict__ AggP, const float* __restrict__ Usb,
    const float* __restrict__ B2, const float* __restrict__ invd,
    const float* __restrict__ F, const float* __restrict__ Wroot,
    const float* __restrict__ broot, const float* __restrict__ Wih,
    const float* __restrict__ Whh, const float* __restrict__ bih,
    const float* __restrict__ bhh, float* __restrict__ Fout) {
    int lane = threadIdx.x & 63, wv = threadIdx.x >> 6;
    int nq = blockIdx.x * 16 + wv * 4;

    float fv[4], uv[4], aa[4], rt[4], bt[4];
#pragma unroll
    for (int q = 0; q < 4; ++q) {
        size_t idx = (size_t)(nq + q) * 64 + lane;
        fv[q] = F[idx];
        uv[q] = Usb[idx];
        float s = 0.f;
#pragma unroll
        for (int ks = 0; ks < 8; ++ks) s += AggP[(size_t)ks * NN * 64 + idx];
        aa[q] = s;
        rt[q] = broot[lane];
        bt[q] = 0.f;
    }
#pragma unroll 8
    for (int k = 0; k < 64; ++k) {
        float wr = Wroot[k * 64 + lane];
        float b2 = B2[k * 64 + lane];
#pragma unroll
        for (int q = 0; q < 4; ++q) {
            rt[q] = fmaf(bcast(fv[q], k), wr, rt[q]);
            bt[q] = fmaf(bcast(uv[q], k), b2, bt[q]);
        }
    }
    float m[4];
#pragma unroll
    for (int q = 0; q < 4; ++q)
        m[q] = fmaxf((aa[q] + bt[q]) * invd[nq + q] + rt[q], 0.f);

    float sr[4], sz[4], gn[4], gh[4];
#pragma unroll
    for (int q = 0; q < 4; ++q) {
        sr[q] = bih[lane] + bhh[lane];
        sz[q] = bih[64 + lane] + bhh[64 + lane];
        gn[q] = bih[128 + lane];
        gh[q] = bhh[128 + lane];
    }
#pragma unroll 8
    for (int k = 0; k < 64; ++k) {
        float wi0 = Wih[k * 192 + lane];
        float wi1 = Wih[k * 192 + 64 + lane];
        float wi2 = Wih[k * 192 + 128 + lane];
        float wh0 = Whh[k * 192 + lane];
        float wh1 = Whh[k * 192 + 64 + lane];
        float wh2 = Whh[k * 192 + 128 + lane];
#pragma unroll
        for (int q = 0; q < 4; ++q) {
            float mk = bcast(m[q], k), hk = bcast(fv[q], k);
            sr[q] = fmaf(mk, wi0, fmaf(hk, wh0, sr[q]));
            sz[q] = fmaf(mk, wi1, fmaf(hk, wh1, sz[q]));
            gn[q] = fmaf(mk, wi2, gn[q]);
            gh[q] = fmaf(hk, wh2, gh[q]);
        }
    }
#pragma unroll
    for (int q = 0; q < 4; ++q) {
        float rr = 1.f / (1.f + __expf(-sr[q]));
        float zz = 1.f / (1.f + __expf(-sz[q]));
        float ng = tanhf(gn[q] + rr * gh[q]);
        Fout[(size_t)(nq + q) * 64 + lane] = (1.f - zz) * ng + zz * fv[q];
    }
}

// ---------------- final ----------------
__global__ __launch_bounds__(256) void k_final(const float* __restrict__ F,
                                               const float* __restrict__ W1,
                                               const float* __restrict__ b1f,
                                               const float* __restrict__ W2l,
                                               const float* __restrict__ b2f,
                                               float* __restrict__ out) {
    int lane = threadIdx.x & 63, wv = threadIdx.x >> 6;
    int n = blockIdx.x * 4 + wv;
    float fv = F[n * 64 + lane];
    float acc = b1f[lane];
#pragma unroll
    for (int k = 0; k < 64; ++k) acc += bcast(fv, k) * W1[k * 64 + lane];
    acc = fmaxf(acc, 0.f);
    float p = acc * W2l[lane];
#pragma unroll
    for (int off = 32; off; off >>= 1) p += __shfl_xor(p, off, 64);
    if (lane == 0) out[n] = p + b2f[0];
}

extern "C" void kernel_launch(void* const* d_in, const int* in_sizes, int n_in,
                              void* d_out, int out_size, void* d_ws, size_t ws_size,
                              hipStream_t stream) {
    const float* x = (const float*)d_in[0];
    const int* ei = (const int*)d_in[1];
    const float* ea = (const float*)d_in[2];
    const float* l0w = (const float*)d_in[3];
    const float* l0b = (const float*)d_in[4];
    const float* n1w = (const float*)d_in[5];
    const float* n1b = (const float*)d_in[6];
    const float* n2w = (const float*)d_in[7];
    const float* n2b = (const float*)d_in[8];
    const float* cr = (const float*)d_in[9];
    const float* cb = (const float*)d_in[10];
    const float* wih = (const float*)d_in[11];
    const float* whh = (const float*)d_in[12];
    const float* bih = (const float*)d_in[13];
    const float* bhh = (const float*)d_in[14];
    const float* l1w = (const float*)d_in[15];
    const float* l1b = (const float*)d_in[16];
    const float* l2w = (const float*)d_in[17];
    const float* l2b = (const float*)d_in[18];

    char* w = (char*)d_ws;
    size_t off = 0;
    float* F0 = (float*)(w + off); off += (size_t)NN * 64 * 4;
    float* F1 = (float*)(w + off); off += (size_t)NN * 64 * 4;
    float* hE = (float*)(w + off); off += (size_t)NE * 64 * 4;
    ushort* W2FH = (ushort*)(w + off); off += (size_t)64 * 4096 * 2;
    ushort* W2FL = (ushort*)(w + off); off += (size_t)64 * 4096 * 2;
    ushort* GH = (ushort*)(w + off); off += (size_t)NP * 4096 * 2;   // 82 MB
    float* AggP = (float*)(w + off); off += (size_t)8 * NN * 64 * 4; // 20.5 MB
    float* Usb = (float*)(w + off); off += (size_t)NN * 64 * 4;      // 2.5 MB
    float* invd = (float*)(w + off); off += (size_t)NN * 4;
    int* deg = (int*)(w + off); off += (size_t)NN * 4;
    int* rowp = (int*)(w + off); off += (size_t)(NN + 1) * 4 + 252; off &= ~(size_t)255;
    int* fill = (int*)(w + off); off += (size_t)NN * 4;
    int* csrs = (int*)(w + off); off += (size_t)NE * 4;
    int* csre = (int*)(w + off); off += (size_t)NE * 4;

    hipMemsetAsync(deg, 0, NN * 4, stream);
    k_count<<<(NE + 255) / 256, 256, 0, stream>>>(ei, deg);
    k_scan<<<1, 1024, 0, stream>>>(deg, rowp, fill, invd);
    k_fill<<<(NE + 255) / 256, 256, 0, stream>>>(ei, fill, csrs, csre);
    k_w2f<<<1024, 256, 0, stream>>>(n2w, W2FH, W2FL);
    k_edge_h<<<NE / 4, 256, 0, stream>>>(ea, n1w, n1b, hE);
    k_lin0<<<NN / 4, 256, 0, stream>>>(x, l0w, l0b, F0);
    float* Fcur = F0;
    float* Fnxt = F1;
    for (int it = 0; it < 3; ++it) {
        k_gather<<<NN / 4, 256, 0, stream>>>(Fcur, hE, rowp, csrs, csre, GH, Usb);
        k_contract<<<32 * 8, 512, 0, stream>>>(GH, W2FH, W2FL, AggP);
        k_epi<<<NN / 16, 256, 0, stream>>>(AggP, Usb, n2b, invd, Fcur, cr, cb,
                                           wih, whh, bih, bhh, Fnxt);
        float* t = Fcur; Fcur = Fnxt; Fnxt = t;
    }
    k_final<<<NN / 4, 256, 0, stream>>>(Fcur, l1w, l1b, l2w, l2b, (float*)d_out);
}

// Round 12
// 321.971 us; speedup vs baseline: 2.0941x; 1.0035x over previous
//
#include <hip/hip_runtime.h>
#include <hip/hip_bf16.h>

#define NN 10000
#define NP 10240  // GH rows padded: 32 m-chunks x 20 m-groups x 16 rows
#define NE 50000
#define FIN 40
#define FE 10
#define MCH 20    // m-groups per contract m-chunk
// L = 64

typedef float f32x4 __attribute__((ext_vector_type(4)));
typedef short s16x8 __attribute__((ext_vector_type(8)));

__device__ __forceinline__ float bcast(float v, int lane) {
    return __uint_as_float(__builtin_amdgcn_readlane(__float_as_uint(v), lane));
}
__device__ __forceinline__ int bcast_i(int v, int lane) {
    return __builtin_amdgcn_readlane(v, lane);
}
__device__ __forceinline__ ushort f2bf(float f) {
    uint u = __float_as_uint(f);
    uint r = (u + 0x7FFFu + ((u >> 16) & 1u)) >> 16;
    return (ushort)r;
}
__device__ __forceinline__ float bf2f(ushort h) {
    return __uint_as_float(((uint)h) << 16);
}

// ---------------- CSR build ----------------
__global__ void k_count(const int* __restrict__ ei, int* __restrict__ deg) {
    int e = blockIdx.x * 256 + threadIdx.x;
    if (e < NE) atomicAdd(&deg[ei[NE + e]], 1);
}

__global__ __launch_bounds__(1024) void k_scan(const int* __restrict__ deg,
                                               int* __restrict__ rowp,
                                               int* __restrict__ fill,
                                               float* __restrict__ invd) {
    __shared__ int wsum[16];
    __shared__ int chunkbase;
    int tid = threadIdx.x, lane = tid & 63, wv = tid >> 6;
    if (tid == 0) chunkbase = 0;
    __syncthreads();
    for (int base = 0; base < NN; base += 1024) {
        int idx = base + tid;
        int v = (idx < NN) ? deg[idx] : 0;
        int s = v;
#pragma unroll
        for (int off = 1; off < 64; off <<= 1) {
            int t = __shfl_up(s, off, 64);
            if (lane >= off) s += t;
        }
        if (lane == 63) wsum[wv] = s;
        __syncthreads();
        int carry = chunkbase;
        if (wv == 0 && lane < 16) {
            int x = wsum[lane];
#pragma unroll
            for (int off = 1; off < 16; off <<= 1) {
                int t = __shfl_up(x, off, 64);
                if (lane >= off) x += t;
            }
            wsum[lane] = x;  // inclusive over waves
        }
        __syncthreads();
        int wpre = (wv == 0) ? 0 : wsum[wv - 1];
        int incl = carry + wpre + s;
        if (idx < NN) {
            rowp[idx] = incl - v;
            fill[idx] = incl - v;
            invd[idx] = 1.0f / (float)(v > 0 ? v : 1);
        }
        __syncthreads();
        if (tid == 0) chunkbase = carry + wsum[15];
        __syncthreads();
    }
    if (tid == 0) rowp[NN] = NE;
}

__global__ void k_fill(const int* __restrict__ ei, int* __restrict__ fill,
                       int* __restrict__ csrs, int* __restrict__ csre) {
    int e = blockIdx.x * 256 + threadIdx.x;
    if (e < NE) {
        int d = ei[NE + e];
        int p = atomicAdd(&fill[d], 1);
        csrs[p] = ei[e];
        csre[p] = e;
    }
}

// ---------------- W2 split-bf16, transposed to [o][ki] (ki = k*64+i) ----------------
__global__ __launch_bounds__(256) void k_w2f(const float* __restrict__ n2w,
                                             ushort* __restrict__ W2FH,
                                             ushort* __restrict__ W2FL) {
    int lane = threadIdx.x & 63, wvl = threadIdx.x >> 6;
    int ki = blockIdx.x * 4 + wvl;
    float v = n2w[(size_t)ki * 64 + lane];
    ushort hi = f2bf(v);
    ushort lo = f2bf(v - bf2f(hi));
    W2FH[(size_t)lane * 4096 + ki] = hi;
    W2FL[(size_t)lane * 4096 + ki] = lo;
}

// ---------------- edge MLP: hE = relu(edge_attr @ nn1_w + nn1_b) ----------------
__global__ __launch_bounds__(256) void k_edge_h(const float* __restrict__ ea,
                                                const float* __restrict__ w1,
                                                const float* __restrict__ b1,
                                                float* __restrict__ hE) {
    int lane = threadIdx.x & 63, wv = threadIdx.x >> 6;
    int e = blockIdx.x * 4 + wv;
    float av = (lane < FE) ? ea[e * FE + lane] : 0.f;
    float acc = b1[lane];
#pragma unroll
    for (int j = 0; j < FE; ++j) acc += bcast(av, j) * w1[j * 64 + lane];
    hE[e * 64 + lane] = fmaxf(acc, 0.f);
}

// ---------------- lin0 ----------------
__global__ __launch_bounds__(256) void k_lin0(const float* __restrict__ x,
                                              const float* __restrict__ w0,
                                              const float* __restrict__ b0,
                                              float* __restrict__ F) {
    int lane = threadIdx.x & 63, wv = threadIdx.x >> 6;
    int n = blockIdx.x * 4 + wv;
    float xv = (lane < FIN) ? x[n * FIN + lane] : 0.f;
    float acc = b0[lane];
#pragma unroll
    for (int k = 0; k < FIN; ++k) acc += bcast(xv, k) * w0[k * 64 + lane];
    F[n * 64 + lane] = fmaxf(acc, 0.f);
}

// ---------------- gather: G[n][k*64+i] = sum_e hE[e][k]*F[src][i] (bf16 out) ----
__global__ __launch_bounds__(256) void k_gather(
    const float* __restrict__ F, const float* __restrict__ hE,
    const int* __restrict__ rowp, const int* __restrict__ csrs,
    const int* __restrict__ csre,
    ushort* __restrict__ GH, float* __restrict__ Usb) {
    int tid = threadIdx.x, lane = tid & 63, wv = tid >> 6;
    int n = __builtin_amdgcn_readfirstlane(blockIdx.x * 4 + wv);
    int beg = __builtin_amdgcn_readfirstlane(rowp[n]);
    int end = __builtin_amdgcn_readfirstlane(rowp[n + 1]);

    float G[64];
#pragma unroll
    for (int k = 0; k < 64; ++k) G[k] = 0.f;
    float usum = 0.f;
    {
        int p0 = beg + lane;
        int sl = (p0 < end) ? csrs[p0] : 0;
        int el = (p0 < end) ? csre[p0] : 0;
        int nb = min(end - beg, 64);
        for (int j = 0; j < nb; ++j) {
            int s = bcast_i(sl, j);
            int e = bcast_i(el, j);
            float u = F[(size_t)s * 64 + lane];
            float hv = hE[(size_t)e * 64 + lane];
            usum += u;
#pragma unroll
            for (int k = 0; k < 64; ++k) G[k] = fmaf(bcast(hv, k), u, G[k]);
        }
        for (int p = beg + 64; p < end; ++p) {  // deg>64: rare
            int s = __builtin_amdgcn_readfirstlane(csrs[p]);
            int e = __builtin_amdgcn_readfirstlane(csre[p]);
            float u = F[(size_t)s * 64 + lane];
            float hv = hE[(size_t)e * 64 + lane];
            usum += u;
#pragma unroll
            for (int k = 0; k < 64; ++k) G[k] = fmaf(bcast(hv, k), u, G[k]);
        }
    }
    Usb[(size_t)n * 64 + lane] = usum;
    ushort* gout = GH + (size_t)n * 4096 + lane;
#pragma unroll
    for (int k = 0; k < 64; ++k) gout[k * 64] = f2bf(G[k]);
}

// ---------------- contract v4: B-stationary, o-half split, hi/lo-split accs ----
// Grid 512 = 32 mc x 8 ks x 2 oh -> exactly 2 blocks/CU (LDS 65 KB).
// 8 waves = 2 o-tiles x 4 m-quarters. Per pair of m-groups: 4 INDEPENDENT
// acc chains (m0/m1 x hi/lo split -- R10's acc += a*bh; acc += a*bl serial
// pair is gone). 4 waves/SIMD x 4 chains = 16 chains/SIMD vs R10's 4.
// Partials stay 8 (oh halves write disjoint o columns of AggP[ks]).
__global__ __launch_bounds__(512) void k_contract(
    const ushort* __restrict__ GH, const ushort* __restrict__ W2FH,
    const ushort* __restrict__ W2FL, float* __restrict__ AggP) {
    __shared__ __align__(16) ushort BH[32 * 520];  // 33280 B
    __shared__ __align__(16) ushort BL[32 * 520];  // 33280 B
    int tid = threadIdx.x, lane = tid & 63, wv = tid >> 6;
    int oh = blockIdx.x & 1;
    int ks = (blockIdx.x >> 1) & 7;
    int mc = blockIdx.x >> 4;  // 0..31
    int kbase = ks * 512;
    int otile = wv & 1, mq = wv >> 1;  // mq 0..3
    int arow = lane & 15, agrp = lane >> 4;
    int lr = otile * 16 + arow;      // local o row in [0,32)
    int o = oh * 32 + lr;            // global o

    // ---- stage B half (32 o-rows x 512 ki, hi+lo): 4 reps x 512thr x 8 ----
#pragma unroll
    for (int rep = 0; rep < 4; ++rep) {
        int off = rep * 4096 + tid * 8;
        int row = off >> 9, col = off & 511;
        *(s16x8*)&BH[row * 520 + col] =
            *(const s16x8*)&W2FH[(size_t)(oh * 32 + row) * 4096 + kbase + col];
        *(s16x8*)&BL[row * 520 + col] =
            *(const s16x8*)&W2FL[(size_t)(oh * 32 + row) * 4096 + kbase + col];
    }
    __syncthreads();

    int mg0 = mc * MCH;
    int mgend = mg0 + MCH;  // 32*20 = 640 = NP/16 exactly
    float* ap = AggP + (size_t)ks * NN * 64;
    for (int mg = mg0 + mq * 2; mg < mgend; mg += 8) {
        const ushort* pA = GH + (size_t)(mg * 16 + arow) * 4096 + kbase;
        const ushort* pB = GH + (size_t)((mg + 1) * 16 + arow) * 4096 + kbase;
        f32x4 a0h = {0.f, 0.f, 0.f, 0.f};
        f32x4 a0l = {0.f, 0.f, 0.f, 0.f};
        f32x4 a1h = {0.f, 0.f, 0.f, 0.f};
        f32x4 a1l = {0.f, 0.f, 0.f, 0.f};
#pragma unroll 4
        for (int s = 0; s < 16; ++s) {
            int kil = s * 32 + agrp * 8;
            s16x8 a0 = *(const s16x8*)&pA[kil];
            s16x8 a1 = *(const s16x8*)&pB[kil];
            s16x8 bh = *(const s16x8*)&BH[lr * 520 + kil];
            s16x8 bl = *(const s16x8*)&BL[lr * 520 + kil];
            a0h = __builtin_amdgcn_mfma_f32_16x16x32_bf16(a0, bh, a0h, 0, 0, 0);
            a1h = __builtin_amdgcn_mfma_f32_16x16x32_bf16(a1, bh, a1h, 0, 0, 0);
            a0l = __builtin_amdgcn_mfma_f32_16x16x32_bf16(a0, bl, a0l, 0, 0, 0);
            a1l = __builtin_amdgcn_mfma_f32_16x16x32_bf16(a1, bl, a1l, 0, 0, 0);
        }
        f32x4 acc0 = a0h + a0l;
        f32x4 acc1 = a1h + a1l;
        // D row r -> node mg*16 + agrp*4 + r
#pragma unroll
        for (int r = 0; r < 4; ++r) {
            int n0r = mg * 16 + agrp * 4 + r;
            if (n0r < NN) ap[(size_t)n0r * 64 + o] = acc0[r];
            int n1r = (mg + 1) * 16 + agrp * 4 + r;
            if (n1r < NN) ap[(size_t)n1r * 64 + o] = acc1[r];
        }
    }
}

// ---------------- epilogue: sum 8 partials + mean + nn2_b + root + GRU ----------------
__global__ __launch_bounds__(256) void k_epi(
    const float* __restrict__ AggP, const float* __restrict__ Usb,
    const float* __restrict__ B2, const float* __restrict__ invd,
    const float* __restrict__ F, const float* __restrict__ Wroot,
    const float* __restrict__ broot, const float* __restrict__ Wih,
    const float* __restrict__ Whh, const float* __restrict__ bih,
    const float* __restrict__ bhh, float* __restrict__ Fout) {
    int lane = threadIdx.x & 63, wv = threadIdx.x >> 6;
    int nq = blockIdx.x * 16 + wv * 4;

    float fv[4], uv[4], aa[4], rt[4], bt[4];
#pragma unroll
    for (int q = 0; q < 4; ++q) {
        size_t idx = (size_t)(nq + q) * 64 + lane;
        fv[q] = F[idx];
        uv[q] = Usb[idx];
        float s = 0.f;
#pragma unroll
        for (int ks = 0; ks < 8; ++ks) s += AggP[(size_t)ks * NN * 64 + idx];
        aa[q] = s;
        rt[q] = broot[lane];
        bt[q] = 0.f;
    }
#pragma unroll 8
    for (int k = 0; k < 64; ++k) {
        float wr = Wroot[k * 64 + lane];
        float b2 = B2[k * 64 + lane];
#pragma unroll
        for (int q = 0; q < 4; ++q) {
            rt[q] = fmaf(bcast(fv[q], k), wr, rt[q]);
            bt[q] = fmaf(bcast(uv[q], k), b2, bt[q]);
        }
    }
    float m[4];
#pragma unroll
    for (int q = 0; q < 4; ++q)
        m[q] = fmaxf((aa[q] + bt[q]) * invd[nq + q] + rt[q], 0.f);

    float sr[4], sz[4], gn[4], gh[4];
#pragma unroll
    for (int q = 0; q < 4; ++q) {
        sr[q] = bih[lane] + bhh[lane];
        sz[q] = bih[64 + lane] + bhh[64 + lane];
        gn[q] = bih[128 + lane];
        gh[q] = bhh[128 + lane];
    }
#pragma unroll 8
    for (int k = 0; k < 64; ++k) {
        float wi0 = Wih[k * 192 + lane];
        float wi1 = Wih[k * 192 + 64 + lane];
        float wi2 = Wih[k * 192 + 128 + lane];
        float wh0 = Whh[k * 192 + lane];
        float wh1 = Whh[k * 192 + 64 + lane];
        float wh2 = Whh[k * 192 + 128 + lane];
#pragma unroll
        for (int q = 0; q < 4; ++q) {
            float mk = bcast(m[q], k), hk = bcast(fv[q], k);
            sr[q] = fmaf(mk, wi0, fmaf(hk, wh0, sr[q]));
            sz[q] = fmaf(mk, wi1, fmaf(hk, wh1, sz[q]));
            gn[q] = fmaf(mk, wi2, gn[q]);
            gh[q] = fmaf(hk, wh2, gh[q]);
        }
    }
#pragma unroll
    for (int q = 0; q < 4; ++q) {
        float rr = 1.f / (1.f + __expf(-sr[q]));
        float zz = 1.f / (1.f + __expf(-sz[q]));
        float ng = tanhf(gn[q] + rr * gh[q]);
        Fout[(size_t)(nq + q) * 64 + lane] = (1.f - zz) * ng + zz * fv[q];
    }
}

// ---------------- final ----------------
__global__ __launch_bounds__(256) void k_final(const float* __restrict__ F,
                                               const float* __restrict__ W1,
                                               const float* __restrict__ b1f,
                                               const float* __restrict__ W2l,
                                               const float* __restrict__ b2f,
                                               float* __restrict__ out) {
    int lane = threadIdx.x & 63, wv = threadIdx.x >> 6;
    int n = blockIdx.x * 4 + wv;
    float fv = F[n * 64 + lane];
    float acc = b1f[lane];
#pragma unroll
    for (int k = 0; k < 64; ++k) acc += bcast(fv, k) * W1[k * 64 + lane];
    acc = fmaxf(acc, 0.f);
    float p = acc * W2l[lane];
#pragma unroll
    for (int off = 32; off; off >>= 1) p += __shfl_xor(p, off, 64);
    if (lane == 0) out[n] = p + b2f[0];
}

extern "C" void kernel_launch(void* const* d_in, const int* in_sizes, int n_in,
                              void* d_out, int out_size, void* d_ws, size_t ws_size,
                              hipStream_t stream) {
    const float* x = (const float*)d_in[0];
    const int* ei = (const int*)d_in[1];
    const float* ea = (const float*)d_in[2];
    const float* l0w = (const float*)d_in[3];
    const float* l0b = (const float*)d_in[4];
    const float* n1w = (const float*)d_in[5];
    const float* n1b = (const float*)d_in[6];
    const float* n2w = (const float*)d_in[7];
    const float* n2b = (const float*)d_in[8];
    const float* cr = (const float*)d_in[9];
    const float* cb = (const float*)d_in[10];
    const float* wih = (const float*)d_in[11];
    const float* whh = (const float*)d_in[12];
    const float* bih = (const float*)d_in[13];
    const float* bhh = (const float*)d_in[14];
    const float* l1w = (const float*)d_in[15];
    const float* l1b = (const float*)d_in[16];
    const float* l2w = (const float*)d_in[17];
    const float* l2b = (const float*)d_in[18];

    char* w = (char*)d_ws;
    size_t off = 0;
    float* F0 = (float*)(w + off); off += (size_t)NN * 64 * 4;
    float* F1 = (float*)(w + off); off += (size_t)NN * 64 * 4;
    float* hE = (float*)(w + off); off += (size_t)NE * 64 * 4;
    ushort* W2FH = (ushort*)(w + off); off += (size_t)64 * 4096 * 2;
    ushort* W2FL = (ushort*)(w + off); off += (size_t)64 * 4096 * 2;
    ushort* GH = (ushort*)(w + off); off += (size_t)NP * 4096 * 2;   // 84 MB
    float* AggP = (float*)(w + off); off += (size_t)8 * NN * 64 * 4; // 20.5 MB
    float* Usb = (float*)(w + off); off += (size_t)NN * 64 * 4;      // 2.5 MB
    float* invd = (float*)(w + off); off += (size_t)NN * 4;
    int* deg = (int*)(w + off); off += (size_t)NN * 4;
    int* rowp = (int*)(w + off); off += (size_t)(NN + 1) * 4 + 252; off &= ~(size_t)255;
    int* fill = (int*)(w + off); off += (size_t)NN * 4;
    int* csrs = (int*)(w + off); off += (size_t)NE * 4;
    int* csre = (int*)(w + off); off += (size_t)NE * 4;

    hipMemsetAsync(deg, 0, NN * 4, stream);
    k_count<<<(NE + 255) / 256, 256, 0, stream>>>(ei, deg);
    k_scan<<<1, 1024, 0, stream>>>(deg, rowp, fill, invd);
    k_fill<<<(NE + 255) / 256, 256, 0, stream>>>(ei, fill, csrs, csre);
    k_w2f<<<1024, 256, 0, stream>>>(n2w, W2FH, W2FL);
    k_edge_h<<<NE / 4, 256, 0, stream>>>(ea, n1w, n1b, hE);
    k_lin0<<<NN / 4, 256, 0, stream>>>(x, l0w, l0b, F0);
    float* Fcur = F0;
    float* Fnxt = F1;
    for (int it = 0; it < 3; ++it) {
        k_gather<<<NN / 4, 256, 0, stream>>>(Fcur, hE, rowp, csrs, csre, GH, Usb);
        k_contract<<<512, 512, 0, stream>>>(GH, W2FH, W2FL, AggP);
        k_epi<<<NN / 16, 256, 0, stream>>>(AggP, Usb, n2b, invd, Fcur, cr, cb,
                                           wih, whh, bih, bhh, Fnxt);
        float* t = Fcur; Fcur = Fnxt; Fnxt = t;
    }
    k_final<<<NN / 4, 256, 0, stream>>>(Fcur, l1w, l1b, l2w, l2b, (float*)d_out);
}